// Round 1
// 453.928 us; speedup vs baseline: 1.1062x; 1.1062x over previous
//
#include <hip/hip_runtime.h>

constexpr int NH = 16;
constexpr int SEQ = 2048;
constexpr int DMODEL = 2048;
constexpr int HDIM = 128;
constexpr int NB = 2;
constexpr int MTOT = NB * SEQ;                 // 4096
constexpr long NEL = (long)NB * SEQ * DMODEL;  // 8388608 activation elements
constexpr long WEL = (long)DMODEL * DMODEL;    // 4194304 weight elements
// fused-QKV workspace requirement (bytes): 4 activations + 3 weights + bias cat
constexpr size_t FUSED_WS = 2ul * (4 * NEL + 3 * WEL + 12288);

typedef __attribute__((ext_vector_type(8))) __bf16 bf16x8;
typedef __attribute__((ext_vector_type(4))) float f32x4;

__device__ __forceinline__ float bf2f(ushort u) {
  union { uint i; float f; } v; v.i = ((uint)u) << 16; return v.f;
}
__device__ __forceinline__ ushort f2bf(float f) {
  union { float f; uint i; } v; v.f = f;
  uint r = (v.i + 0x7FFFu + ((v.i >> 16) & 1u)) >> 16;
  return (ushort)r;
}
// round-half-up bf16: 2 VALU ops; P>0 so tie bias is negligible (hot path only)
__device__ __forceinline__ ushort f2bf_rhu(float f) {
  union { float f; uint i; } v; v.f = f;
  return (ushort)((v.i + 0x8000u) >> 16);
}

// ---------------------------------------------------------------------------
// fp32 -> bf16 conversion (inputs are float32 per the reference contract).
// ---------------------------------------------------------------------------
__global__ __launch_bounds__(256) void conv_f32_bf16(
    const float* __restrict__ s, ushort* __restrict__ d, int n4) {
  const int i = blockIdx.x * 256 + threadIdx.x;
  if (i < n4) {
    const float4 v = ((const float4*)s)[i];
    ushort4 o;
    o.x = f2bf(v.x); o.y = f2bf(v.y); o.z = f2bf(v.z); o.w = f2bf(v.w);
    ((ushort4*)d)[i] = o;
  }
}

// concat 3 x 2048 fp32 biases for the fused QKV GEMM
__global__ __launch_bounds__(256) void bias_cat(
    const float* __restrict__ a, const float* __restrict__ b,
    const float* __restrict__ c, float* __restrict__ o) {
  const int i = blockIdx.x * 256 + threadIdx.x;  // grid 24 -> 6144
  o[i] = (i < 2048) ? a[i] : (i < 4096) ? b[i - 2048] : c[i - 4096];
}

// ---------------------------------------------------------------------------
// 256x256-tile 8-phase bt-GEMM (m201 template): C[M,N] = A[M,K]@B[N,K]^T+bias.
// 8 waves (2M x 4N), 512 threads, BK=64, 128 KiB LDS double-buffer.
// Wave rows interleaved across tile halves: phase (mh,nh) consumes exactly
// A-half mh and B-half nh -> staggered half-tile lifetimes -> one counted
// vmcnt(6) per K-tile (never 0 in the loop). T2 XOR swizzle applied on the
// per-lane GLOBAL source (global_load_lds writes linearly) and identically
// on the ds_read address. T5 setprio around each 16-MFMA cluster.
// MODE 0: fp32 [M,N]. MODE 1: bf16 scatter to [B,H,S,HD], col>>11 selects
// the tensor (Q/K/V contiguous), serving per-tensor (N=2048) and fused
// (N=6144) launches.
// ---------------------------------------------------------------------------
#define GLDS(src, dst)                                              \
  __builtin_amdgcn_global_load_lds(                                 \
      (const __attribute__((address_space(1))) void*)(src),         \
      (__attribute__((address_space(3))) void*)(dst), 16, 0, 0)

#define STAGE_A(d, mh, kc) do {                                     \
    const ushort* _s = gA + (long)((mh) * 128) * K + (kc) * 64;     \
    ushort* _d = smem + (d) * 16384 + (mh) * 8192 + w * 1024;       \
    GLDS(_s, _d);                                                   \
    GLDS(_s + 8 * (long)K, _d + 512);                               \
  } while (0)

#define STAGE_B(d, nh, kc) do {                                     \
    const ushort* _s = gB + (long)((nh) * 128) * K + (kc) * 64;     \
    ushort* _d = smem + 32768 + (d) * 16384 + (nh) * 8192 + w * 1024; \
    GLDS(_s, _d);                                                   \
    GLDS(_s + 8 * (long)K, _d + 512);                               \
  } while (0)

#define LDA(d, mh) do {                                             \
    const ushort* _p = smem + (d) * 16384 + (mh) * 8192 +           \
                       (wm * 64 + l16) * 64;                        \
    _Pragma("unroll")                                               \
    for (int _i = 0; _i < 4; _i++) {                                \
      afr[_i][0] = *(const bf16x8*)(_p + _i * 1024 + sw0);          \
      afr[_i][1] = *(const bf16x8*)(_p + _i * 1024 + sw1);          \
    }                                                               \
  } while (0)

#define LDB(d, nh) do {                                             \
    const ushort* _p = smem + 32768 + (d) * 16384 + (nh) * 8192 +   \
                       (wn * 32 + l16) * 64;                        \
    _Pragma("unroll")                                               \
    for (int _j = 0; _j < 2; _j++) {                                \
      bfr[nh][_j][0] = *(const bf16x8*)(_p + _j * 1024 + sw0);      \
      bfr[nh][_j][1] = *(const bf16x8*)(_p + _j * 1024 + sw1);      \
    }                                                               \
  } while (0)

#define MMA(mh, nh) do {                                            \
    __builtin_amdgcn_s_setprio(1);                                  \
    _Pragma("unroll")                                               \
    for (int _i = 0; _i < 4; _i++)                                  \
      _Pragma("unroll")                                             \
      for (int _j = 0; _j < 2; _j++) {                              \
        acc[mh][_i][nh][_j] = __builtin_amdgcn_mfma_f32_16x16x32_bf16( \
            afr[_i][0], bfr[nh][_j][0], acc[mh][_i][nh][_j], 0, 0, 0); \
        acc[mh][_i][nh][_j] = __builtin_amdgcn_mfma_f32_16x16x32_bf16( \
            afr[_i][1], bfr[nh][_j][1], acc[mh][_i][nh][_j], 0, 0, 0); \
      }                                                             \
    __builtin_amdgcn_s_setprio(0);                                  \
  } while (0)

#define BARX() __builtin_amdgcn_s_barrier()
#define WAITV(n) asm volatile("s_waitcnt vmcnt(" #n ")" ::: "memory")
#define WAITL() asm volatile("s_waitcnt lgkmcnt(0)" ::: "memory")

template <int MODE>
__global__ __launch_bounds__(512, 2) void gemm256(
    const ushort* __restrict__ A, const ushort* __restrict__ Bw,
    const float* __restrict__ bias, void* __restrict__ Cv,
    int M, int N, int K) {
  // LDS layout (ushort units): A bufs [2][256][64] at 0, B bufs at 32768.
  // Physical row = 64 ush (128 B); 16B slot s of logical col c: s = (c>>3)
  // stored at slot s ^ (row&7)  (involution; staging pre-applies it on the
  // global source so global_load_lds's linear write lands swizzled).
  __shared__ __align__(16) ushort smem[65536];  // 128 KiB -> 1 block/CU
  const int tid = threadIdx.x;
  const int w = tid >> 6, lane = tid & 63;
  const int quad = lane >> 4, l16 = lane & 15;
  const int wm = w >> 2, wn = w & 3;  // 2M x 4N waves
  const int nbn = N >> 8;
  // XCD-aware swizzle (grid is always a multiple of 8 here)
  const int cpx = (int)gridDim.x >> 3;
  const int swz = (blockIdx.x & 7) * cpx + (blockIdx.x >> 3);
  const int bm = swz / nbn, bn = swz % nbn;
  const int m0 = bm << 8, n0 = bn << 8;
  const int KT = K >> 6;  // 64-wide K-tiles (K=2048 -> 32, even)

  // staging source: thread covers row (w*16 + lane/8 [+8 for 2nd load]),
  // 16B chunk (lane&7) XOR (row&7)=(lane>>3)  == pre-swizzled source
  const int srow = (w << 4) + (lane >> 3);
  const int scol = ((lane & 7) ^ (lane >> 3)) << 3;
  const ushort* gA = A + (long)(m0 + srow) * K + scol;
  const ushort* gB = Bw + (long)(n0 + srow) * K + scol;
  // ds_read swizzled slot offsets for kk=0/1: slot=(kk*4+quad)^(l16&7)
  const int sw0 = ((quad ^ (lane & 7)) << 3);
  const int sw1 = (((4 + quad) ^ (lane & 7)) << 3);

  f32x4 acc[2][4][2][2] = {};  // [mh][mfrag][nh][nfrag]
  bf16x8 afr[4][2];            // current A-half frags [mfrag][kk]
  bf16x8 bfr[2][2][2];         // both B-half frags [nh][nfrag][kk]

  // Prologue: tile0 {A0,B0,B1,A1} + tile1 {A0,B0}; tile0 landed, 2 in flight.
  STAGE_A(0, 0, 0); STAGE_B(0, 0, 0); STAGE_B(0, 1, 0); STAGE_A(0, 1, 0);
  STAGE_A(1, 0, 1); STAGE_B(1, 0, 1);
  WAITV(4);
  BARX();

  for (int t = 0; t < KT; t += 2) {
    const int c2 = (t + 2 < KT) ? t + 2 : 0;            // phantom -> L2-hot
    const int c3 = (t + 3 < KT) ? t + 3 : (t + 3 - KT);
    // ---- tile t (buf0) ----
    // ph0: stage B1(t+1); boundary wait (leaves 3 half-tiles in flight)
    STAGE_B(1, 1, t + 1); WAITV(6); BARX();
    LDA(0, 0); LDB(0, 0); WAITL();
    MMA(0, 0); BARX();
    // ph1
    LDB(0, 1); STAGE_A(1, 1, t + 1); BARX(); WAITL();
    MMA(0, 1); BARX();
    // ph2
    LDA(0, 1); STAGE_A(0, 0, c2); BARX(); WAITL();
    MMA(1, 0); BARX();
    // ph3
    STAGE_B(0, 0, c2); BARX();
    MMA(1, 1); BARX();
    // ---- tile t+1 (buf1) ----
    // ph4
    STAGE_B(0, 1, c2); WAITV(6); BARX();
    LDA(1, 0); LDB(1, 0); WAITL();
    MMA(0, 0); BARX();
    // ph5
    LDB(1, 1); STAGE_A(0, 1, c2); BARX(); WAITL();
    MMA(0, 1); BARX();
    // ph6
    LDA(1, 1); STAGE_A(1, 0, c3); BARX(); WAITL();
    MMA(1, 0); BARX();
    // ph7
    STAGE_B(1, 0, c3); BARX();
    MMA(1, 1); BARX();
  }

  // Epilogue: C layout col=l16, row=quad*4+r; rows/cols interleaved by half.
#pragma unroll
  for (int mh = 0; mh < 2; mh++)
#pragma unroll
    for (int i = 0; i < 4; i++) {
      const int rbase = m0 + mh * 128 + wm * 64 + i * 16 + quad * 4;
#pragma unroll
      for (int nh = 0; nh < 2; nh++)
#pragma unroll
        for (int j = 0; j < 2; j++) {
          const int col = n0 + nh * 128 + wn * 32 + j * 16 + l16;
          const float bv = bias[col];
#pragma unroll
          for (int r = 0; r < 4; r++) {
            const int row = rbase + r;
            const float v = acc[mh][i][nh][j][r] + bv;
            if (MODE == 0) {
              ((float*)Cv)[(long)row * N + col] = v;
            } else {
              const int b = row >> 11, s = row & (SEQ - 1);
              const int h = (col >> 7) & 15, hd = col & (HDIM - 1);
              const long off = (long)(col >> 11) * NEL +
                  ((long)(b * NH + h) * SEQ + s) * HDIM + hd;
              ((ushort*)Cv)[off] = f2bf(v);
            }
          }
        }
    }
}

// ---------------------------------------------------------------------------
// RoPE in-place on bf16 Q,K in [B,H,S,HD]; reference swaps sin/cos.
// Q additionally pre-scaled by 1/sqrt(HD) so attn needs no score scaling.
// ---------------------------------------------------------------------------
__global__ __launch_bounds__(256) void rope_qk(ushort* Q, ushort* Kt) {
  const int gid = blockIdx.x * 256 + threadIdx.x;
  const int n = gid & 4194303;
  const bool isK = (gid >= 4194304);
  ushort* ptr = isK ? Kt : Q;
  const float qs = isK ? 1.0f : 0.08838834764831845f;  // 1/sqrt(128)
  const int p = n & 63;
  const int s = (n >> 6) & (SEQ - 1);
  const int bh = n >> 17;
  const long idx = (long)bh * (SEQ * HDIM) + (long)s * HDIM + p;
  const float invf = exp2f(-(float)p * 0.2076205059304601f);  // log2(1e4)/64
  const float f = (float)s * invf;
  float sn, cs;
  sincosf(f, &sn, &cs);
  const float x1 = bf2f(ptr[idx]);
  const float x2 = bf2f(ptr[idx + 64]);
  ptr[idx]      = f2bf((x1 * sn - x2 * cs) * qs);
  ptr[idx + 64] = f2bf((x2 * sn + x1 * cs) * qs);
}

// ---------------------------------------------------------------------------
// V transpose per head: [B,H,S,HD] -> [B,H,HD,S], 64x64 LDS tiles.
// ---------------------------------------------------------------------------
__global__ __launch_bounds__(256) void transpose_v(const ushort* __restrict__ V,
                                                   ushort* __restrict__ VT) {
  __shared__ ushort lT[64 * 65];
  const int bh = blockIdx.x >> 6;
  const int rem = blockIdx.x & 63;
  const int t0 = (rem >> 1) << 6, d0 = (rem & 1) << 6;
  const ushort* vb = V + (long)bh * (SEQ * HDIM);
  ushort* ob = VT + (long)bh * (SEQ * HDIM);
  const int tid = threadIdx.x;
#pragma unroll
  for (int it = 0; it < 16; it++) {
    const int idx = it * 256 + tid;
    const int r = idx >> 6, c = idx & 63;
    lT[c * 65 + r] = vb[(long)(t0 + r) * HDIM + d0 + c];
  }
  __syncthreads();
#pragma unroll
  for (int it = 0; it < 16; it++) {
    const int idx = it * 256 + tid;
    const int r = idx >> 6, c = idx & 63;
    ob[(long)(d0 + r) * SEQ + t0 + c] = lT[r * 65 + c];
  }
}

// ---------------------------------------------------------------------------
// Flash attention, fixed-max softmax, S^T-form QK.
// Block = 64 q-rows of one head; wave w: q-half (w&1), t-half (w>>1),
// i.e. a 32q x 32t P-tile per wave per 64-t iteration.
// KEY restructure (R5): compute S^T = K*Q^T (A=K, B=Q). C-layout then gives
// q across lanes (col=l16) and t in registers (row=quad*4+r), so the P
// spill to LDS layout [q][t] uses one base register + imm offsets (no
// per-store swizzle math), and PV reads P back as a single ds_read_b128
// A-fragment per q-subtile. l accumulated via ones-MFMA (C rows = q, matches
// O rows). ctx written to bf16 [B,S,D].
// ---------------------------------------------------------------------------
__global__ __launch_bounds__(256) void attn(const ushort* __restrict__ Q,
                                            const ushort* __restrict__ Kp,
                                            const ushort* __restrict__ VT,
                                            ushort* __restrict__ ctx) {
  __shared__ __align__(16) ushort smem[23040];      // 45 KB
  ushort* lK = smem;                                // [64 t][136]
  ushort* lV = smem + 64 * 136;                     // [128 d][72]
  ushort* lP = smem + 64 * 136 + 128 * 72;          // 4 x [32 q][40 t]
  const int tid = threadIdx.x;
  const int wave = tid >> 6, lane = tid & 63;
  const int quad = lane >> 4, l16 = lane & 15;
  // XCD-aware swizzle: 128 consecutive local ids (4 heads) per XCD.
  const int xcd = blockIdx.x & 7, loc = blockIdx.x >> 3;
  const int bh = xcd * 4 + (loc >> 5), qt = loc & 31;
  const long hb = (long)bh * (SEQ * HDIM);
  const int b = bh >> 4, h = bh & 15;
  const int qh = wave & 1, th = wave >> 1;
  ushort* myP = lP + wave * (32 * 40);

  // Q fragments (B-operand: n=q=l16, k=hd=quad*8+j) for both 16-q subtiles
  bf16x8 qa[2][4];
#pragma unroll
  for (int qq = 0; qq < 2; qq++)
#pragma unroll
    for (int c = 0; c < 4; c++)
      qa[qq][c] = *(const bf16x8*)(
          Q + hb + (long)(qt * 64 + qh * 32 + qq * 16 + l16) * HDIM +
          c * 32 + (quad << 3));

  f32x4 o[2][8] = {};
  f32x4 lacc[2] = {};
  bf16x8 ones;
#pragma unroll
  for (int i = 0; i < 8; i++) ones[i] = (__bf16)1.0f;

  // staging pointers: advance by +64 t-rows (K) / +64 t-cols (VT) per iter
  const ushort* kSrc = Kp + hb + (long)(tid >> 4) * HDIM + (tid & 15) * 8;
  const ushort* vSrc = VT + hb + (long)(tid >> 3) * SEQ + (tid & 7) * 8;
  ushort* kDst = lK + (tid >> 4) * 136 + (tid & 15) * 8;
  ushort* vDst = lV + (tid >> 3) * 72 + (tid & 7) * 8;
  // loop-invariant read bases
  const ushort* kRow = lK + (th * 32 + l16) * 136 + (quad << 3);
  const ushort* vRow = lV + l16 * 72 + th * 32 + (quad << 3);
  const ushort* pRow = myP + l16 * 40 + (quad << 3);
  ushort* pWr = myP + l16 * 40 + (quad << 2);

  for (int t0 = 0; t0 < SEQ; t0 += 64) {
    __syncthreads();  // protect staging overwrite vs prior reads
#pragma unroll
    for (int it = 0; it < 4; it++) {
      *(bf16x8*)(kDst + it * (16 * 136)) =
          *(const bf16x8*)(kSrc + (long)it * (16 * HDIM));
      *(bf16x8*)(vDst + it * (32 * 72)) =
          *(const bf16x8*)(vSrc + (long)it * (32 * SEQ));
    }
    kSrc += 64 * HDIM;
    vSrc += 64;
    __syncthreads();  // staging visible

    // S^T = K Q^T over this wave's 32x32 tile: A=K (m=t), B=Q (n=q)
    f32x4 st[2][2] = {};  // [tt][qq]
#pragma unroll
    for (int kc = 0; kc < 4; kc++)
#pragma unroll
      for (int tt = 0; tt < 2; tt++) {
        const bf16x8 ka = *(const bf16x8*)(kRow + tt * (16 * 136) + kc * 32);
#pragma unroll
        for (int qq = 0; qq < 2; qq++)
          st[tt][qq] = __builtin_amdgcn_mfma_f32_16x16x32_bf16(
              ka, qa[qq][kc], st[tt][qq], 0, 0, 0);
      }

    // p = exp(s): lane's q = qq*16+l16 (col), t = tt*16+quad*4+r (row reg)
    // -> stores to [q][t] LDS are base + imm offsets only.
#pragma unroll
    for (int qq = 0; qq < 2; qq++)
#pragma unroll
      for (int tt = 0; tt < 2; tt++)
#pragma unroll
        for (int r = 0; r < 4; r++)
          pWr[qq * (16 * 40) + tt * 16 + r] = f2bf_rhu(__expf(st[tt][qq][r]));

    __syncthreads();  // fence P writes (TBAA) + cross-use ordering

    // PV: A=P (m=q, k=t from one b128), B=VT rows (n=d, k=t)
    bf16x8 pa[2];
#pragma unroll
    for (int qq = 0; qq < 2; qq++) {
      pa[qq] = *(const bf16x8*)(pRow + qq * (16 * 40));
      lacc[qq] = __builtin_amdgcn_mfma_f32_16x16x32_bf16(
          pa[qq], ones, lacc[qq], 0, 0, 0);
    }
#pragma unroll
    for (int nt = 0; nt < 8; nt++) {
      const bf16x8 vb = *(const bf16x8*)(vRow + nt * (16 * 72));
#pragma unroll
      for (int qq = 0; qq < 2; qq++)
        o[qq][nt] = __builtin_amdgcn_mfma_f32_16x16x32_bf16(
            pa[qq], vb, o[qq][nt], 0, 0, 0);
    }
  }

  // Merge t-halves: waves 2,3 publish (O, l); waves 0,1 add and store.
  __syncthreads();
  float* mb = (float*)smem;  // 2 regions x 64 lanes x 73 floats = 37376 B
  if (wave >= 2) {
    float* p = mb + ((wave - 2) * 64 + lane) * 73;
#pragma unroll
    for (int qq = 0; qq < 2; qq++) {
#pragma unroll
      for (int nt = 0; nt < 8; nt++)
#pragma unroll
        for (int r = 0; r < 4; r++) p[qq * 32 + nt * 4 + r] = o[qq][nt][r];
#pragma unroll
      for (int r = 0; r < 4; r++) p[64 + qq * 4 + r] = lacc[qq][r];
    }
  }
  __syncthreads();
  if (wave < 2) {
    const float* p = mb + (wave * 64 + lane) * 73;
#pragma unroll
    for (int qq = 0; qq < 2; qq++) {
#pragma unroll
      for (int nt = 0; nt < 8; nt++)
#pragma unroll
        for (int r = 0; r < 4; r++) o[qq][nt][r] += p[qq * 32 + nt * 4 + r];
#pragma unroll
      for (int r = 0; r < 4; r++) lacc[qq][r] += p[64 + qq * 4 + r];
    }
#pragma unroll
    for (int qq = 0; qq < 2; qq++)
#pragma unroll
      for (int r = 0; r < 4; r++) {
        const float inv = 1.0f / lacc[qq][r];
        const int s = qt * 64 + qh * 32 + qq * 16 + quad * 4 + r;
        const long base = ((long)(b * SEQ + s)) * DMODEL + h * HDIM;
#pragma unroll
        for (int nt = 0; nt < 8; nt++)
          ctx[base + nt * 16 + l16] = f2bf(o[qq][nt][r] * inv);
      }
  }
}

// ---------------------------------------------------------------------------
extern "C" void kernel_launch(void* const* d_in, const int* in_sizes, int n_in,
                              void* d_out, int out_size, void* d_ws, size_t ws_size,
                              hipStream_t stream) {
  const float* hid = (const float*)d_in[0];
  const float* Wq = (const float*)d_in[1];
  const float* bq = (const float*)d_in[2];
  const float* Wk = (const float*)d_in[3];
  const float* bk = (const float*)d_in[4];
  const float* Wv = (const float*)d_in[5];
  const float* bv = (const float*)d_in[6];
  const float* Wo = (const float*)d_in[7];
  const float* bo = (const float*)d_in[8];
  float* out = (float*)d_out;
  ushort* ws = (ushort*)d_ws;

  ushort* qw   = ws;            // [B,H,S,HD] bf16  (Q/K/V contiguous!)
  ushort* kw   = ws + NEL;
  ushort* vw   = ws + 2 * NEL;  // reused as ctx after transpose_v
  ushort* hidB = ws + 3 * NEL;  // hidden bf16; reused as VT after QKV GEMM(s)
  ushort* wB   = ws + 4 * NEL;  // weight bf16: 1x or 3x [D,D]

  dim3 blk(256);
  dim3 blkG(512);
  conv_f32_bf16<<<(int)(NEL / 4 / 256), blk, 0, stream>>>(hid, hidB, NEL / 4);

  if (ws_size >= FUSED_WS) {
    // fused QKV: one N=6144 GEMM, (4096/256)*(6144/256) = 384 blocks
    conv_f32_bf16<<<(int)(WEL / 4 / 256), blk, 0, stream>>>(Wq, wB, WEL / 4);
    conv_f32_bf16<<<(int)(WEL / 4 / 256), blk, 0, stream>>>(Wk, wB + WEL, WEL / 4);
    conv_f32_bf16<<<(int)(WEL / 4 / 256), blk, 0, stream>>>(Wv, wB + 2 * WEL, WEL / 4);
    float* bc = (float*)(wB + 3 * WEL);
    bias_cat<<<24, blk, 0, stream>>>(bq, bk, bv, bc);
    gemm256<1><<<384, blkG, 0, stream>>>(hidB, wB, bc, qw, MTOT, 3 * DMODEL, DMODEL);
  } else {
    conv_f32_bf16<<<(int)(WEL / 4 / 256), blk, 0, stream>>>(Wq, wB, WEL / 4);
    gemm256<1><<<128, blkG, 0, stream>>>(hidB, wB, bq, qw, MTOT, DMODEL, DMODEL);
    conv_f32_bf16<<<(int)(WEL / 4 / 256), blk, 0, stream>>>(Wk, wB, WEL / 4);
    gemm256<1><<<128, blkG, 0, stream>>>(hidB, wB, bk, kw, MTOT, DMODEL, DMODEL);
    conv_f32_bf16<<<(int)(WEL / 4 / 256), blk, 0, stream>>>(Wv, wB, WEL / 4);
    gemm256<1><<<128, blkG, 0, stream>>>(hidB, wB, bv, vw, MTOT, DMODEL, DMODEL);
  }

  rope_qk<<<32768, blk, 0, stream>>>(qw, kw);

  // V^T into the hidB slot (hidden no longer needed as GEMM input)
  ushort* vtw = hidB;
  transpose_v<<<2048, blk, 0, stream>>>(vw, vtw);

  // attn writes ctx into the vw slot (V superseded by VT)
  ushort* cw = vw;
  attn<<<1024, blk, 0, stream>>>(qw, kw, vtw, cw);

  conv_f32_bf16<<<(int)(WEL / 4 / 256), blk, 0, stream>>>(Wo, wB, WEL / 4);
  gemm256<0><<<128, blkG, 0, stream>>>(cw, wB, bo, out, MTOT, DMODEL, DMODEL);
}

// Round 2
// 434.705 us; speedup vs baseline: 1.1552x; 1.0442x over previous
//
#include <hip/hip_runtime.h>

constexpr int NH = 16;
constexpr int SEQ = 2048;
constexpr int DMODEL = 2048;
constexpr int HDIM = 128;
constexpr int NB = 2;
constexpr int MTOT = NB * SEQ;                 // 4096
constexpr long NEL = (long)NB * SEQ * DMODEL;  // 8388608 activation elements
constexpr long WEL = (long)DMODEL * DMODEL;    // 4194304 weight elements
// fused-QKV workspace requirement (bytes): 4 activations + 3 weights + bias cat
constexpr size_t FUSED_WS = 2ul * (4 * NEL + 3 * WEL + 12288);

typedef __attribute__((ext_vector_type(8))) __bf16 bf16x8;
typedef __attribute__((ext_vector_type(4))) float f32x4;

__device__ __forceinline__ float bf2f(ushort u) {
  union { uint i; float f; } v; v.i = ((uint)u) << 16; return v.f;
}
__device__ __forceinline__ ushort f2bf(float f) {
  union { float f; uint i; } v; v.f = f;
  uint r = (v.i + 0x7FFFu + ((v.i >> 16) & 1u)) >> 16;
  return (ushort)r;
}
// round-half-up bf16: 2 VALU ops; P>0 so tie bias is negligible (hot path only)
__device__ __forceinline__ ushort f2bf_rhu(float f) {
  union { float f; uint i; } v; v.f = f;
  return (ushort)((v.i + 0x8000u) >> 16);
}
__device__ __forceinline__ float fast_exp2(float x) {
#if __has_builtin(__builtin_amdgcn_exp2f)
  return __builtin_amdgcn_exp2f(x);
#else
  float r;
  asm volatile("v_exp_f32 %0, %1\n\ts_nop 0" : "=v"(r) : "v"(x));
  return r;
#endif
}

// ---------------------------------------------------------------------------
// fp32 -> bf16 conversion (inputs are float32 per the reference contract).
// ---------------------------------------------------------------------------
__global__ __launch_bounds__(256) void conv_f32_bf16(
    const float* __restrict__ s, ushort* __restrict__ d, int n4) {
  const int i = blockIdx.x * 256 + threadIdx.x;
  if (i < n4) {
    const float4 v = ((const float4*)s)[i];
    ushort4 o;
    o.x = f2bf(v.x); o.y = f2bf(v.y); o.z = f2bf(v.z); o.w = f2bf(v.w);
    ((ushort4*)d)[i] = o;
  }
}

// concat 3 x 2048 fp32 biases for the fused QKV GEMM
__global__ __launch_bounds__(256) void bias_cat(
    const float* __restrict__ a, const float* __restrict__ b,
    const float* __restrict__ c, float* __restrict__ o) {
  const int i = blockIdx.x * 256 + threadIdx.x;  // grid 24 -> 6144
  o[i] = (i < 2048) ? a[i] : (i < 4096) ? b[i - 2048] : c[i - 4096];
}

// ---------------------------------------------------------------------------
// 256x256-tile 8-phase bt-GEMM (m201 template): C[M,N] = A[M,K]@B[N,K]^T+bias.
// 8 waves (2M x 4N), 512 threads, BK=64, 128 KiB LDS double-buffer.
// Counted vmcnt(6) per K-tile; T2 XOR swizzle on global source + ds_read;
// T5 setprio around each 16-MFMA cluster. MODE 0: fp32 [M,N]. MODE 1: bf16
// scatter to [B,H,S,HD], col>>11 selects the tensor (Q/K/V contiguous).
// ---------------------------------------------------------------------------
#define GLDS(src, dst)                                              \
  __builtin_amdgcn_global_load_lds(                                 \
      (const __attribute__((address_space(1))) void*)(src),         \
      (__attribute__((address_space(3))) void*)(dst), 16, 0, 0)

#define STAGE_A(d, mh, kc) do {                                     \
    const ushort* _s = gA + (long)((mh) * 128) * K + (kc) * 64;     \
    ushort* _d = smem + (d) * 16384 + (mh) * 8192 + w * 1024;       \
    GLDS(_s, _d);                                                   \
    GLDS(_s + 8 * (long)K, _d + 512);                               \
  } while (0)

#define STAGE_B(d, nh, kc) do {                                     \
    const ushort* _s = gB + (long)((nh) * 128) * K + (kc) * 64;     \
    ushort* _d = smem + 32768 + (d) * 16384 + (nh) * 8192 + w * 1024; \
    GLDS(_s, _d);                                                   \
    GLDS(_s + 8 * (long)K, _d + 512);                               \
  } while (0)

#define LDA(d, mh) do {                                             \
    const ushort* _p = smem + (d) * 16384 + (mh) * 8192 +           \
                       (wm * 64 + l16) * 64;                        \
    _Pragma("unroll")                                               \
    for (int _i = 0; _i < 4; _i++) {                                \
      afr[_i][0] = *(const bf16x8*)(_p + _i * 1024 + sw0);          \
      afr[_i][1] = *(const bf16x8*)(_p + _i * 1024 + sw1);          \
    }                                                               \
  } while (0)

#define LDB(d, nh) do {                                             \
    const ushort* _p = smem + 32768 + (d) * 16384 + (nh) * 8192 +   \
                       (wn * 32 + l16) * 64;                        \
    _Pragma("unroll")                                               \
    for (int _j = 0; _j < 2; _j++) {                                \
      bfr[nh][_j][0] = *(const bf16x8*)(_p + _j * 1024 + sw0);      \
      bfr[nh][_j][1] = *(const bf16x8*)(_p + _j * 1024 + sw1);      \
    }                                                               \
  } while (0)

#define MMA(mh, nh) do {                                            \
    __builtin_amdgcn_s_setprio(1);                                  \
    _Pragma("unroll")                                               \
    for (int _i = 0; _i < 4; _i++)                                  \
      _Pragma("unroll")                                             \
      for (int _j = 0; _j < 2; _j++) {                              \
        acc[mh][_i][nh][_j] = __builtin_amdgcn_mfma_f32_16x16x32_bf16( \
            afr[_i][0], bfr[nh][_j][0], acc[mh][_i][nh][_j], 0, 0, 0); \
        acc[mh][_i][nh][_j] = __builtin_amdgcn_mfma_f32_16x16x32_bf16( \
            afr[_i][1], bfr[nh][_j][1], acc[mh][_i][nh][_j], 0, 0, 0); \
      }                                                             \
    __builtin_amdgcn_s_setprio(0);                                  \
  } while (0)

#define BARX() __builtin_amdgcn_s_barrier()
#define WAITV(n) asm volatile("s_waitcnt vmcnt(" #n ")" ::: "memory")
#define WAITL() asm volatile("s_waitcnt lgkmcnt(0)" ::: "memory")

template <int MODE>
__global__ __launch_bounds__(512, 2) void gemm256(
    const ushort* __restrict__ A, const ushort* __restrict__ Bw,
    const float* __restrict__ bias, void* __restrict__ Cv,
    int M, int N, int K) {
  __shared__ __align__(16) ushort smem[65536];  // 128 KiB -> 1 block/CU
  const int tid = threadIdx.x;
  const int w = tid >> 6, lane = tid & 63;
  const int quad = lane >> 4, l16 = lane & 15;
  const int wm = w >> 2, wn = w & 3;  // 2M x 4N waves
  const int nbn = N >> 8;
  // XCD-aware swizzle (grid is always a multiple of 8 here)
  const int cpx = (int)gridDim.x >> 3;
  const int swz = (blockIdx.x & 7) * cpx + (blockIdx.x >> 3);
  const int bm = swz / nbn, bn = swz % nbn;
  const int m0 = bm << 8, n0 = bn << 8;
  const int KT = K >> 6;  // 64-wide K-tiles (K=2048 -> 32, even)

  const int srow = (w << 4) + (lane >> 3);
  const int scol = ((lane & 7) ^ (lane >> 3)) << 3;
  const ushort* gA = A + (long)(m0 + srow) * K + scol;
  const ushort* gB = Bw + (long)(n0 + srow) * K + scol;
  const int sw0 = ((quad ^ (lane & 7)) << 3);
  const int sw1 = (((4 + quad) ^ (lane & 7)) << 3);

  f32x4 acc[2][4][2][2] = {};  // [mh][mfrag][nh][nfrag]
  bf16x8 afr[4][2];            // current A-half frags [mfrag][kk]
  bf16x8 bfr[2][2][2];         // both B-half frags [nh][nfrag][kk]

  // Prologue: tile0 {A0,B0,B1,A1} + tile1 {A0,B0}; tile0 landed, 2 in flight.
  STAGE_A(0, 0, 0); STAGE_B(0, 0, 0); STAGE_B(0, 1, 0); STAGE_A(0, 1, 0);
  STAGE_A(1, 0, 1); STAGE_B(1, 0, 1);
  WAITV(4);
  BARX();

  for (int t = 0; t < KT; t += 2) {
    const int c2 = (t + 2 < KT) ? t + 2 : 0;            // phantom -> L2-hot
    const int c3 = (t + 3 < KT) ? t + 3 : (t + 3 - KT);
    // ---- tile t (buf0) ----
    STAGE_B(1, 1, t + 1); WAITV(6); BARX();
    LDA(0, 0); LDB(0, 0); WAITL();
    MMA(0, 0); BARX();
    LDB(0, 1); STAGE_A(1, 1, t + 1); BARX(); WAITL();
    MMA(0, 1); BARX();
    LDA(0, 1); STAGE_A(0, 0, c2); BARX(); WAITL();
    MMA(1, 0); BARX();
    STAGE_B(0, 0, c2); BARX();
    MMA(1, 1); BARX();
    // ---- tile t+1 (buf1) ----
    STAGE_B(0, 1, c2); WAITV(6); BARX();
    LDA(1, 0); LDB(1, 0); WAITL();
    MMA(0, 0); BARX();
    LDB(1, 1); STAGE_A(0, 1, c2); BARX(); WAITL();
    MMA(0, 1); BARX();
    LDA(1, 1); STAGE_A(1, 0, c3); BARX(); WAITL();
    MMA(1, 0); BARX();
    STAGE_B(1, 0, c3); BARX();
    MMA(1, 1); BARX();
  }

#pragma unroll
  for (int mh = 0; mh < 2; mh++)
#pragma unroll
    for (int i = 0; i < 4; i++) {
      const int rbase = m0 + mh * 128 + wm * 64 + i * 16 + quad * 4;
#pragma unroll
      for (int nh = 0; nh < 2; nh++)
#pragma unroll
        for (int j = 0; j < 2; j++) {
          const int col = n0 + nh * 128 + wn * 32 + j * 16 + l16;
          const float bv = bias[col];
#pragma unroll
          for (int r = 0; r < 4; r++) {
            const int row = rbase + r;
            const float v = acc[mh][i][nh][j][r] + bv;
            if (MODE == 0) {
              ((float*)Cv)[(long)row * N + col] = v;
            } else {
              const int b = row >> 11, s = row & (SEQ - 1);
              const int h = (col >> 7) & 15, hd = col & (HDIM - 1);
              const long off = (long)(col >> 11) * NEL +
                  ((long)(b * NH + h) * SEQ + s) * HDIM + hd;
              ((ushort*)Cv)[off] = f2bf(v);
            }
          }
        }
    }
}

// ---------------------------------------------------------------------------
// RoPE in-place on bf16 Q,K in [B,H,S,HD]; reference swaps sin/cos.
// Q pre-scaled by log2(e)/sqrt(HD) so attn uses bare exp2 for softmax.
// sin/cos via revolution-domain v_sin/v_cos (explicit fract reduction);
// phase error ~1.3e-4 rad << bf16 quantization.
// ---------------------------------------------------------------------------
__global__ __launch_bounds__(256) void rope_qk(ushort* Q, ushort* Kt) {
  const int gid = blockIdx.x * 256 + threadIdx.x;
  const int n = gid & 4194303;
  const bool isK = (gid >= 4194304);
  ushort* ptr = isK ? Kt : Q;
  const float qs = isK ? 1.0f : 0.12751743f;  // log2(e)/sqrt(128)
  const int p = n & 63;
  const int s = (n >> 6) & (SEQ - 1);
  const int bh = n >> 17;
  const long idx = (long)bh * (SEQ * HDIM) + (long)s * HDIM + p;
  // inv_freq / (2*pi): angle in revolutions
  const float invf_rev =
      fast_exp2(-(float)p * 0.2076205059304601f) * 0.15915494309189535f;
  float rev = (float)s * invf_rev;
  rev -= floorf(rev);
  const float sn = __builtin_amdgcn_sinf(rev);
  const float cs = __builtin_amdgcn_cosf(rev);
  const float x1 = bf2f(ptr[idx]);
  const float x2 = bf2f(ptr[idx + 64]);
  ptr[idx]      = f2bf((x1 * sn - x2 * cs) * qs);
  ptr[idx + 64] = f2bf((x2 * sn + x1 * cs) * qs);
}

// ---------------------------------------------------------------------------
// V transpose per head: [B,H,S,HD] -> [B,H,HD,S], 64x64 LDS tiles.
// ---------------------------------------------------------------------------
__global__ __launch_bounds__(256) void transpose_v(const ushort* __restrict__ V,
                                                   ushort* __restrict__ VT) {
  __shared__ ushort lT[64 * 65];
  const int bh = blockIdx.x >> 6;
  const int rem = blockIdx.x & 63;
  const int t0 = (rem >> 1) << 6, d0 = (rem & 1) << 6;
  const ushort* vb = V + (long)bh * (SEQ * HDIM);
  ushort* ob = VT + (long)bh * (SEQ * HDIM);
  const int tid = threadIdx.x;
#pragma unroll
  for (int it = 0; it < 16; it++) {
    const int idx = it * 256 + tid;
    const int r = idx >> 6, c = idx & 63;
    lT[c * 65 + r] = vb[(long)(t0 + r) * HDIM + d0 + c];
  }
  __syncthreads();
#pragma unroll
  for (int it = 0; it < 16; it++) {
    const int idx = it * 256 + tid;
    const int r = idx >> 6, c = idx & 63;
    ob[(long)(d0 + r) * SEQ + t0 + c] = lT[r * 65 + c];
  }
}

// ---------------------------------------------------------------------------
// Flash attention, fixed-max softmax, S^T-form QK (S^T = K*Q^T).
// R2 restructure: double-buffered K/V staging (T14 async reg split) -> ONE
// barrier per t-iteration (was 3). Next tile's global loads issue at iter
// start (latency hidden under QK+softmax+PV); ds_writes land at iter end
// into the alternate buffer. P scratch is wave-private: write->read ordering
// is lgkmcnt(0)+sched_barrier only (no block barrier); the asm memory
// clobber also defeats the ushort<->bf16 TBAA reorder hazard. P stores
// packed as ushort4 (r-values are consecutive t). Softmax uses bare exp2
// (Q pre-scaled by log2e in rope). T5 setprio around MFMA clusters.
// LDS 80 KB exactly -> 2 blocks/CU.
// ---------------------------------------------------------------------------
__global__ __launch_bounds__(256, 2) void attn(const ushort* __restrict__ Q,
                                               const ushort* __restrict__ Kp,
                                               const ushort* __restrict__ VT,
                                               ushort* __restrict__ ctx) {
  // lK[2]: [64][136] @ 0 / 8704 ; lV[2]: [128][72] @ 17408 / 26624 ;
  // lP: 4 x [32][40] @ 35840.  Total 40960 ushort = 80 KiB.
  __shared__ __align__(16) ushort smem[40960];
  const int tid = threadIdx.x;
  const int wave = tid >> 6, lane = tid & 63;
  const int quad = lane >> 4, l16 = lane & 15;
  // XCD-aware swizzle: 128 consecutive local ids (4 heads) per XCD.
  const int xcd = blockIdx.x & 7, loc = blockIdx.x >> 3;
  const int bh = xcd * 4 + (loc >> 5), qt = loc & 31;
  const long hb = (long)bh * (SEQ * HDIM);
  const int b = bh >> 4, h = bh & 15;
  const int qh = wave & 1, th = wave >> 1;
  ushort* myP = smem + 35840 + wave * (32 * 40);

  // Q fragments (B-operand: n=q=l16, k=hd=quad*8+j) for both 16-q subtiles
  bf16x8 qa[2][4];
#pragma unroll
  for (int qq = 0; qq < 2; qq++)
#pragma unroll
    for (int c = 0; c < 4; c++)
      qa[qq][c] = *(const bf16x8*)(
          Q + hb + (long)(qt * 64 + qh * 32 + qq * 16 + l16) * HDIM +
          c * 32 + (quad << 3));

  f32x4 o[2][8] = {};
  f32x4 lacc[2] = {};
  bf16x8 ones;
#pragma unroll
  for (int i = 0; i < 8; i++) ones[i] = (__bf16)1.0f;

  // staging addressing (per-thread), buffer-relative
  const ushort* kSrc = Kp + hb + (long)(tid >> 4) * HDIM + (tid & 15) * 8;
  const ushort* vSrc = VT + hb + (long)(tid >> 3) * SEQ + (tid & 7) * 8;
  const int kOff = (tid >> 4) * 136 + (tid & 15) * 8;
  const int vOff = (tid >> 3) * 72 + (tid & 7) * 8;

  // prologue: stage tile 0 into buf 0
  {
    bf16x8 kR[4], vR[4];
#pragma unroll
    for (int it = 0; it < 4; it++) {
      kR[it] = *(const bf16x8*)(kSrc + (long)it * (16 * HDIM));
      vR[it] = *(const bf16x8*)(vSrc + (long)it * (32 * SEQ));
    }
    kSrc += 64 * HDIM; vSrc += 64;
#pragma unroll
    for (int it = 0; it < 4; it++) {
      *(bf16x8*)(smem + kOff + it * (16 * 136)) = kR[it];
      *(bf16x8*)(smem + 17408 + vOff + it * (32 * 72)) = vR[it];
    }
  }
  __syncthreads();

  for (int t0 = 0; t0 < SEQ; t0 += 64) {
    const int cur = (t0 >> 6) & 1;
    ushort* cK = cur ? smem + 8704 : smem;
    ushort* cV = cur ? smem + 26624 : smem + 17408;
    ushort* nK = cur ? smem : smem + 8704;
    ushort* nV = cur ? smem + 17408 : smem + 26624;
    const bool more = (t0 + 64 < SEQ);

    // issue next tile's global loads (consumed after PV)
    bf16x8 kR[4], vR[4];
    if (more) {
#pragma unroll
      for (int it = 0; it < 4; it++) {
        kR[it] = *(const bf16x8*)(kSrc + (long)it * (16 * HDIM));
        vR[it] = *(const bf16x8*)(vSrc + (long)it * (32 * SEQ));
      }
      kSrc += 64 * HDIM; vSrc += 64;
    }

    // S^T = K Q^T over this wave's 32x32 tile: A=K (m=t), B=Q (n=q)
    const ushort* kRow = cK + (th * 32 + l16) * 136 + (quad << 3);
    f32x4 st[2][2] = {};  // [tt][qq]
    __builtin_amdgcn_s_setprio(1);
#pragma unroll
    for (int kc = 0; kc < 4; kc++)
#pragma unroll
      for (int tt = 0; tt < 2; tt++) {
        const bf16x8 ka = *(const bf16x8*)(kRow + tt * (16 * 136) + kc * 32);
#pragma unroll
        for (int qq = 0; qq < 2; qq++)
          st[tt][qq] = __builtin_amdgcn_mfma_f32_16x16x32_bf16(
              ka, qa[qq][kc], st[tt][qq], 0, 0, 0);
      }
    __builtin_amdgcn_s_setprio(0);

    // p = 2^s (Q carries log2e): lane's q = qq*16+l16 (col),
    // t = tt*16+quad*4+r (row reg) -> one b64 store per (qq,tt).
    ushort* pW = myP + l16 * 40 + (quad << 2);
#pragma unroll
    for (int qq = 0; qq < 2; qq++)
#pragma unroll
      for (int tt = 0; tt < 2; tt++) {
        ushort4 pk;
        pk.x = f2bf_rhu(fast_exp2(st[tt][qq][0]));
        pk.y = f2bf_rhu(fast_exp2(st[tt][qq][1]));
        pk.z = f2bf_rhu(fast_exp2(st[tt][qq][2]));
        pk.w = f2bf_rhu(fast_exp2(st[tt][qq][3]));
        *(ushort4*)(pW + qq * (16 * 40) + tt * 16) = pk;
      }
    WAITL();                               // P is wave-private: lgkm only
    __builtin_amdgcn_sched_barrier(0);     // rule 18: pin vs hoisting

    // PV: A=P (m=q, k=t from one b128), B=VT rows (n=d, k=t)
    const ushort* pRow = myP + l16 * 40 + (quad << 3);
    const ushort* vRow = cV + l16 * 72 + th * 32 + (quad << 3);
    bf16x8 pa[2];
    __builtin_amdgcn_s_setprio(1);
#pragma unroll
    for (int qq = 0; qq < 2; qq++) {
      pa[qq] = *(const bf16x8*)(pRow + qq * (16 * 40));
      lacc[qq] = __builtin_amdgcn_mfma_f32_16x16x32_bf16(
          pa[qq], ones, lacc[qq], 0, 0, 0);
    }
#pragma unroll
    for (int nt = 0; nt < 8; nt++) {
      const bf16x8 vb = *(const bf16x8*)(vRow + nt * (16 * 72));
#pragma unroll
      for (int qq = 0; qq < 2; qq++)
        o[qq][nt] = __builtin_amdgcn_mfma_f32_16x16x32_bf16(
            pa[qq], vb, o[qq][nt], 0, 0, 0);
    }
    __builtin_amdgcn_s_setprio(0);

    // land staged regs in the alternate buffer; single barrier per iter:
    // guards next-iter reads of nK/nV AND next-iter overwrites of cK/cV.
    if (more) {
#pragma unroll
      for (int it = 0; it < 4; it++) {
        *(bf16x8*)(nK + kOff + it * (16 * 136)) = kR[it];
        *(bf16x8*)(nV + vOff + it * (32 * 72)) = vR[it];
      }
    }
    __syncthreads();
  }

  // Merge t-halves: waves 2,3 publish (O, l); waves 0,1 add and store.
  float* mb = (float*)smem;  // 2 regions x 64 lanes x 73 floats = 37376 B
  if (wave >= 2) {
    float* p = mb + ((wave - 2) * 64 + lane) * 73;
#pragma unroll
    for (int qq = 0; qq < 2; qq++) {
#pragma unroll
      for (int nt = 0; nt < 8; nt++)
#pragma unroll
        for (int r = 0; r < 4; r++) p[qq * 32 + nt * 4 + r] = o[qq][nt][r];
#pragma unroll
      for (int r = 0; r < 4; r++) p[64 + qq * 4 + r] = lacc[qq][r];
    }
  }
  __syncthreads();
  if (wave < 2) {
    const float* p = mb + (wave * 64 + lane) * 73;
#pragma unroll
    for (int qq = 0; qq < 2; qq++) {
#pragma unroll
      for (int nt = 0; nt < 8; nt++)
#pragma unroll
        for (int r = 0; r < 4; r++) o[qq][nt][r] += p[qq * 32 + nt * 4 + r];
#pragma unroll
      for (int r = 0; r < 4; r++) lacc[qq][r] += p[64 + qq * 4 + r];
    }
#pragma unroll
    for (int qq = 0; qq < 2; qq++)
#pragma unroll
      for (int r = 0; r < 4; r++) {
        const float inv = 1.0f / lacc[qq][r];
        const int s = qt * 64 + qh * 32 + qq * 16 + quad * 4 + r;
        const long base = ((long)(b * SEQ + s)) * DMODEL + h * HDIM;
#pragma unroll
        for (int nt = 0; nt < 8; nt++)
          ctx[base + nt * 16 + l16] = f2bf(o[qq][nt][r] * inv);
      }
  }
}

// ---------------------------------------------------------------------------
extern "C" void kernel_launch(void* const* d_in, const int* in_sizes, int n_in,
                              void* d_out, int out_size, void* d_ws, size_t ws_size,
                              hipStream_t stream) {
  const float* hid = (const float*)d_in[0];
  const float* Wq = (const float*)d_in[1];
  const float* bq = (const float*)d_in[2];
  const float* Wk = (const float*)d_in[3];
  const float* bk = (const float*)d_in[4];
  const float* Wv = (const float*)d_in[5];
  const float* bv = (const float*)d_in[6];
  const float* Wo = (const float*)d_in[7];
  const float* bo = (const float*)d_in[8];
  float* out = (float*)d_out;
  ushort* ws = (ushort*)d_ws;

  ushort* qw   = ws;            // [B,H,S,HD] bf16  (Q/K/V contiguous!)
  ushort* kw   = ws + NEL;
  ushort* vw   = ws + 2 * NEL;  // reused as ctx after transpose_v
  ushort* hidB = ws + 3 * NEL;  // hidden bf16; reused as VT after QKV GEMM(s)
  ushort* wB   = ws + 4 * NEL;  // weight bf16: 1x or 3x [D,D]

  dim3 blk(256);
  dim3 blkG(512);
  conv_f32_bf16<<<(int)(NEL / 4 / 256), blk, 0, stream>>>(hid, hidB, NEL / 4);

  if (ws_size >= FUSED_WS) {
    // fused QKV: one N=6144 GEMM, (4096/256)*(6144/256) = 384 blocks
    conv_f32_bf16<<<(int)(WEL / 4 / 256), blk, 0, stream>>>(Wq, wB, WEL / 4);
    conv_f32_bf16<<<(int)(WEL / 4 / 256), blk, 0, stream>>>(Wk, wB + WEL, WEL / 4);
    conv_f32_bf16<<<(int)(WEL / 4 / 256), blk, 0, stream>>>(Wv, wB + 2 * WEL, WEL / 4);
    float* bc = (float*)(wB + 3 * WEL);
    bias_cat<<<24, blk, 0, stream>>>(bq, bk, bv, bc);
    gemm256<1><<<384, blkG, 0, stream>>>(hidB, wB, bc, qw, MTOT, 3 * DMODEL, DMODEL);
  } else {
    conv_f32_bf16<<<(int)(WEL / 4 / 256), blk, 0, stream>>>(Wq, wB, WEL / 4);
    gemm256<1><<<128, blkG, 0, stream>>>(hidB, wB, bq, qw, MTOT, DMODEL, DMODEL);
    conv_f32_bf16<<<(int)(WEL / 4 / 256), blk, 0, stream>>>(Wk, wB, WEL / 4);
    gemm256<1><<<128, blkG, 0, stream>>>(hidB, wB, bk, kw, MTOT, DMODEL, DMODEL);
    conv_f32_bf16<<<(int)(WEL / 4 / 256), blk, 0, stream>>>(Wv, wB, WEL / 4);
    gemm256<1><<<128, blkG, 0, stream>>>(hidB, wB, bv, vw, MTOT, DMODEL, DMODEL);
  }

  rope_qk<<<32768, blk, 0, stream>>>(qw, kw);

  // V^T into the hidB slot (hidden no longer needed as GEMM input)
  ushort* vtw = hidB;
  transpose_v<<<2048, blk, 0, stream>>>(vw, vtw);

  // attn writes ctx into the vw slot (V superseded by VT)
  ushort* cw = vw;
  attn<<<1024, blk, 0, stream>>>(qw, kw, vtw, cw);

  conv_f32_bf16<<<(int)(WEL / 4 / 256), blk, 0, stream>>>(Wo, wB, WEL / 4);
  gemm256<0><<<128, blkG, 0, stream>>>(cw, wB, bo, out, MTOT, DMODEL, DMODEL);
}

// Round 3
// 431.386 us; speedup vs baseline: 1.1640x; 1.0077x over previous
//
#include <hip/hip_runtime.h>

constexpr int NH = 16;
constexpr int SEQ = 2048;
constexpr int DMODEL = 2048;
constexpr int HDIM = 128;
constexpr int NB = 2;
constexpr int MTOT = NB * SEQ;                 // 4096
constexpr long NEL = (long)NB * SEQ * DMODEL;  // 8388608 activation elements
constexpr long WEL = (long)DMODEL * DMODEL;    // 4194304 weight elements
// fused-QKV workspace requirement (bytes): 4 activations + 3 weights + bias cat
constexpr size_t FUSED_WS = 2ul * (4 * NEL + 3 * WEL + 12288);

typedef __attribute__((ext_vector_type(8))) __bf16 bf16x8;
typedef __attribute__((ext_vector_type(4))) float f32x4;

__device__ __forceinline__ float bf2f(ushort u) {
  union { uint i; float f; } v; v.i = ((uint)u) << 16; return v.f;
}
__device__ __forceinline__ ushort f2bf(float f) {
  union { float f; uint i; } v; v.f = f;
  uint r = (v.i + 0x7FFFu + ((v.i >> 16) & 1u)) >> 16;
  return (ushort)r;
}
// round-half-up bf16: 2 VALU ops; P>0 so tie bias is negligible (hot path only)
__device__ __forceinline__ ushort f2bf_rhu(float f) {
  union { float f; uint i; } v; v.f = f;
  return (ushort)((v.i + 0x8000u) >> 16);
}
__device__ __forceinline__ float fast_exp2(float x) {
#if __has_builtin(__builtin_amdgcn_exp2f)
  return __builtin_amdgcn_exp2f(x);
#else
  float r;
  asm volatile("v_exp_f32 %0, %1\n\ts_nop 0" : "=v"(r) : "v"(x));
  return r;
#endif
}

// ---------------------------------------------------------------------------
// fp32 -> bf16 conversion (inputs are float32 per the reference contract).
// ---------------------------------------------------------------------------
__global__ __launch_bounds__(256) void conv_f32_bf16(
    const float* __restrict__ s, ushort* __restrict__ d, int n4) {
  const int i = blockIdx.x * 256 + threadIdx.x;
  if (i < n4) {
    const float4 v = ((const float4*)s)[i];
    ushort4 o;
    o.x = f2bf(v.x); o.y = f2bf(v.y); o.z = f2bf(v.z); o.w = f2bf(v.w);
    ((ushort4*)d)[i] = o;
  }
}

// concat 3 x 2048 fp32 biases for the fused QKV GEMM
__global__ __launch_bounds__(256) void bias_cat(
    const float* __restrict__ a, const float* __restrict__ b,
    const float* __restrict__ c, float* __restrict__ o) {
  const int i = blockIdx.x * 256 + threadIdx.x;  // grid 24 -> 6144
  o[i] = (i < 2048) ? a[i] : (i < 4096) ? b[i - 2048] : c[i - 4096];
}

// ---------------------------------------------------------------------------
// 256x256-tile 8-phase bt-GEMM (m201 template): C[M,N] = A[M,K]@B[N,K]^T+bias.
// 8 waves (2M x 4N), 512 threads, BK=64, 128 KiB LDS double-buffer.
// Counted vmcnt(6) per K-tile; T2 XOR swizzle on global source + ds_read;
// T5 setprio around each 16-MFMA cluster.
// R3: two-level XCD partition — 8 rectangular regions (2 along M x 4 along
// N), each (nbm/2) x (nbn/4) blocks, column-major within a region. Cuts
// per-XCD compulsory L2-miss traffic from (2 A-panels + ALL B-panels) to a
// near-square footprint: fused 26->14 MB/XCD (FETCH 184->~112 MB).
// MODE 0: fp32 [M,N]. MODE 1: bf16 scatter to [B,H,S,HD], col>>11 selects
// the tensor (Q/K/V contiguous).
// ---------------------------------------------------------------------------
#define GLDS(src, dst)                                              \
  __builtin_amdgcn_global_load_lds(                                 \
      (const __attribute__((address_space(1))) void*)(src),         \
      (__attribute__((address_space(3))) void*)(dst), 16, 0, 0)

#define STAGE_A(d, mh, kc) do {                                     \
    const ushort* _s = gA + (long)((mh) * 128) * K + (kc) * 64;     \
    ushort* _d = smem + (d) * 16384 + (mh) * 8192 + w * 1024;       \
    GLDS(_s, _d);                                                   \
    GLDS(_s + 8 * (long)K, _d + 512);                               \
  } while (0)

#define STAGE_B(d, nh, kc) do {                                     \
    const ushort* _s = gB + (long)((nh) * 128) * K + (kc) * 64;     \
    ushort* _d = smem + 32768 + (d) * 16384 + (nh) * 8192 + w * 1024; \
    GLDS(_s, _d);                                                   \
    GLDS(_s + 8 * (long)K, _d + 512);                               \
  } while (0)

#define LDA(d, mh) do {                                             \
    const ushort* _p = smem + (d) * 16384 + (mh) * 8192 +           \
                       (wm * 64 + l16) * 64;                        \
    _Pragma("unroll")                                               \
    for (int _i = 0; _i < 4; _i++) {                                \
      afr[_i][0] = *(const bf16x8*)(_p + _i * 1024 + sw0);          \
      afr[_i][1] = *(const bf16x8*)(_p + _i * 1024 + sw1);          \
    }                                                               \
  } while (0)

#define LDB(d, nh) do {                                             \
    const ushort* _p = smem + 32768 + (d) * 16384 + (nh) * 8192 +   \
                       (wn * 32 + l16) * 64;                        \
    _Pragma("unroll")                                               \
    for (int _j = 0; _j < 2; _j++) {                                \
      bfr[nh][_j][0] = *(const bf16x8*)(_p + _j * 1024 + sw0);      \
      bfr[nh][_j][1] = *(const bf16x8*)(_p + _j * 1024 + sw1);      \
    }                                                               \
  } while (0)

#define MMA(mh, nh) do {                                            \
    __builtin_amdgcn_s_setprio(1);                                  \
    _Pragma("unroll")                                               \
    for (int _i = 0; _i < 4; _i++)                                  \
      _Pragma("unroll")                                             \
      for (int _j = 0; _j < 2; _j++) {                              \
        acc[mh][_i][nh][_j] = __builtin_amdgcn_mfma_f32_16x16x32_bf16( \
            afr[_i][0], bfr[nh][_j][0], acc[mh][_i][nh][_j], 0, 0, 0); \
        acc[mh][_i][nh][_j] = __builtin_amdgcn_mfma_f32_16x16x32_bf16( \
            afr[_i][1], bfr[nh][_j][1], acc[mh][_i][nh][_j], 0, 0, 0); \
      }                                                             \
    __builtin_amdgcn_s_setprio(0);                                  \
  } while (0)

#define BARX() __builtin_amdgcn_s_barrier()
#define WAITV(n) asm volatile("s_waitcnt vmcnt(" #n ")" ::: "memory")
#define WAITL() asm volatile("s_waitcnt lgkmcnt(0)" ::: "memory")

template <int MODE>
__global__ __launch_bounds__(512, 2) void gemm256(
    const ushort* __restrict__ A, const ushort* __restrict__ Bw,
    const float* __restrict__ bias, void* __restrict__ Cv,
    int M, int N, int K) {
  __shared__ __align__(16) ushort smem[65536];  // 128 KiB -> 1 block/CU
  const int tid = threadIdx.x;
  const int w = tid >> 6, lane = tid & 63;
  const int quad = lane >> 4, l16 = lane & 15;
  const int wm = w >> 2, wn = w & 3;  // 2M x 4N waves
  const int nbm = M >> 8, nbn = N >> 8;
  // Two-level XCD partition: 8 regions (2 x 4), each rm x rn blocks,
  // column-major within a region (consecutive blocks share a B-panel).
  const int rm = nbm >> 1, rn = nbn >> 2;
  const int xcd = blockIdx.x & 7, loc = blockIdx.x >> 3;
  const int bm = (xcd >> 2) * rm + (loc % rm);
  const int bn = (xcd & 3) * rn + (loc / rm);
  const int m0 = bm << 8, n0 = bn << 8;
  const int KT = K >> 6;  // 64-wide K-tiles (K=2048 -> 32, even)

  const int srow = (w << 4) + (lane >> 3);
  const int scol = ((lane & 7) ^ (lane >> 3)) << 3;
  const ushort* gA = A + (long)(m0 + srow) * K + scol;
  const ushort* gB = Bw + (long)(n0 + srow) * K + scol;
  const int sw0 = ((quad ^ (lane & 7)) << 3);
  const int sw1 = (((4 + quad) ^ (lane & 7)) << 3);

  f32x4 acc[2][4][2][2] = {};  // [mh][mfrag][nh][nfrag]
  bf16x8 afr[4][2];            // current A-half frags [mfrag][kk]
  bf16x8 bfr[2][2][2];         // both B-half frags [nh][nfrag][kk]

  // Prologue: tile0 {A0,B0,B1,A1} + tile1 {A0,B0}; tile0 landed, 2 in flight.
  STAGE_A(0, 0, 0); STAGE_B(0, 0, 0); STAGE_B(0, 1, 0); STAGE_A(0, 1, 0);
  STAGE_A(1, 0, 1); STAGE_B(1, 0, 1);
  WAITV(4);
  BARX();

  for (int t = 0; t < KT; t += 2) {
    const int c2 = (t + 2 < KT) ? t + 2 : 0;            // phantom -> L2-hot
    const int c3 = (t + 3 < KT) ? t + 3 : (t + 3 - KT);
    // ---- tile t (buf0) ----
    STAGE_B(1, 1, t + 1); WAITV(6); BARX();
    LDA(0, 0); LDB(0, 0); WAITL();
    MMA(0, 0); BARX();
    LDB(0, 1); STAGE_A(1, 1, t + 1); BARX(); WAITL();
    MMA(0, 1); BARX();
    LDA(0, 1); STAGE_A(0, 0, c2); BARX(); WAITL();
    MMA(1, 0); BARX();
    STAGE_B(0, 0, c2); BARX();
    MMA(1, 1); BARX();
    // ---- tile t+1 (buf1) ----
    STAGE_B(0, 1, c2); WAITV(6); BARX();
    LDA(1, 0); LDB(1, 0); WAITL();
    MMA(0, 0); BARX();
    LDB(1, 1); STAGE_A(0, 1, c2); BARX(); WAITL();
    MMA(0, 1); BARX();
    LDA(1, 1); STAGE_A(1, 0, c3); BARX(); WAITL();
    MMA(1, 0); BARX();
    STAGE_B(1, 0, c3); BARX();
    MMA(1, 1); BARX();
  }

#pragma unroll
  for (int mh = 0; mh < 2; mh++)
#pragma unroll
    for (int i = 0; i < 4; i++) {
      const int rbase = m0 + mh * 128 + wm * 64 + i * 16 + quad * 4;
#pragma unroll
      for (int nh = 0; nh < 2; nh++)
#pragma unroll
        for (int j = 0; j < 2; j++) {
          const int col = n0 + nh * 128 + wn * 32 + j * 16 + l16;
          const float bv = bias[col];
#pragma unroll
          for (int r = 0; r < 4; r++) {
            const int row = rbase + r;
            const float v = acc[mh][i][nh][j][r] + bv;
            if (MODE == 0) {
              ((float*)Cv)[(long)row * N + col] = v;
            } else {
              const int b = row >> 11, s = row & (SEQ - 1);
              const int h = (col >> 7) & 15, hd = col & (HDIM - 1);
              const long off = (long)(col >> 11) * NEL +
                  ((long)(b * NH + h) * SEQ + s) * HDIM + hd;
              ((ushort*)Cv)[off] = f2bf(v);
            }
          }
        }
    }
}

// ---------------------------------------------------------------------------
// RoPE in-place on bf16 Q,K in [B,H,S,HD]; reference swaps sin/cos.
// Q pre-scaled by log2(e)/sqrt(HD) so attn uses bare exp2 for softmax.
// sin/cos via revolution-domain v_sin/v_cos (explicit fract reduction);
// phase error ~1.3e-4 rad << bf16 quantization.
// ---------------------------------------------------------------------------
__global__ __launch_bounds__(256) void rope_qk(ushort* Q, ushort* Kt) {
  const int gid = blockIdx.x * 256 + threadIdx.x;
  const int n = gid & 4194303;
  const bool isK = (gid >= 4194304);
  ushort* ptr = isK ? Kt : Q;
  const float qs = isK ? 1.0f : 0.12751743f;  // log2(e)/sqrt(128)
  const int p = n & 63;
  const int s = (n >> 6) & (SEQ - 1);
  const int bh = n >> 17;
  const long idx = (long)bh * (SEQ * HDIM) + (long)s * HDIM + p;
  // inv_freq / (2*pi): angle in revolutions
  const float invf_rev =
      fast_exp2(-(float)p * 0.2076205059304601f) * 0.15915494309189535f;
  float rev = (float)s * invf_rev;
  rev -= floorf(rev);
  const float sn = __builtin_amdgcn_sinf(rev);
  const float cs = __builtin_amdgcn_cosf(rev);
  const float x1 = bf2f(ptr[idx]);
  const float x2 = bf2f(ptr[idx + 64]);
  ptr[idx]      = f2bf((x1 * sn - x2 * cs) * qs);
  ptr[idx + 64] = f2bf((x2 * sn + x1 * cs) * qs);
}

// ---------------------------------------------------------------------------
// V transpose per head: [B,H,S,HD] -> [B,H,HD,S], 64x64 LDS tiles.
// ---------------------------------------------------------------------------
__global__ __launch_bounds__(256) void transpose_v(const ushort* __restrict__ V,
                                                   ushort* __restrict__ VT) {
  __shared__ ushort lT[64 * 65];
  const int bh = blockIdx.x >> 6;
  const int rem = blockIdx.x & 63;
  const int t0 = (rem >> 1) << 6, d0 = (rem & 1) << 6;
  const ushort* vb = V + (long)bh * (SEQ * HDIM);
  ushort* ob = VT + (long)bh * (SEQ * HDIM);
  const int tid = threadIdx.x;
#pragma unroll
  for (int it = 0; it < 16; it++) {
    const int idx = it * 256 + tid;
    const int r = idx >> 6, c = idx & 63;
    lT[c * 65 + r] = vb[(long)(t0 + r) * HDIM + d0 + c];
  }
  __syncthreads();
#pragma unroll
  for (int it = 0; it < 16; it++) {
    const int idx = it * 256 + tid;
    const int r = idx >> 6, c = idx & 63;
    ob[(long)(d0 + r) * SEQ + t0 + c] = lT[r * 65 + c];
  }
}

// ---------------------------------------------------------------------------
// Flash attention, fixed-max softmax, S^T-form QK (S^T = K*Q^T).
// Double-buffered K/V staging (T14 async reg split) -> ONE barrier per
// t-iteration. P scratch wave-private (lgkmcnt-only ordering). Softmax is
// bare exp2 (Q pre-scaled by log2e in rope). T5 setprio on MFMA clusters.
// LDS 80 KB exactly -> 2 blocks/CU.
// ---------------------------------------------------------------------------
__global__ __launch_bounds__(256, 2) void attn(const ushort* __restrict__ Q,
                                               const ushort* __restrict__ Kp,
                                               const ushort* __restrict__ VT,
                                               ushort* __restrict__ ctx) {
  // lK[2]: [64][136] @ 0 / 8704 ; lV[2]: [128][72] @ 17408 / 26624 ;
  // lP: 4 x [32][40] @ 35840.  Total 40960 ushort = 80 KiB.
  __shared__ __align__(16) ushort smem[40960];
  const int tid = threadIdx.x;
  const int wave = tid >> 6, lane = tid & 63;
  const int quad = lane >> 4, l16 = lane & 15;
  // XCD-aware swizzle: 128 consecutive local ids (4 heads) per XCD.
  const int xcd = blockIdx.x & 7, loc = blockIdx.x >> 3;
  const int bh = xcd * 4 + (loc >> 5), qt = loc & 31;
  const long hb = (long)bh * (SEQ * HDIM);
  const int b = bh >> 4, h = bh & 15;
  const int qh = wave & 1, th = wave >> 1;
  ushort* myP = smem + 35840 + wave * (32 * 40);

  // Q fragments (B-operand: n=q=l16, k=hd=quad*8+j) for both 16-q subtiles
  bf16x8 qa[2][4];
#pragma unroll
  for (int qq = 0; qq < 2; qq++)
#pragma unroll
    for (int c = 0; c < 4; c++)
      qa[qq][c] = *(const bf16x8*)(
          Q + hb + (long)(qt * 64 + qh * 32 + qq * 16 + l16) * HDIM +
          c * 32 + (quad << 3));

  f32x4 o[2][8] = {};
  f32x4 lacc[2] = {};
  bf16x8 ones;
#pragma unroll
  for (int i = 0; i < 8; i++) ones[i] = (__bf16)1.0f;

  // staging addressing (per-thread), buffer-relative
  const ushort* kSrc = Kp + hb + (long)(tid >> 4) * HDIM + (tid & 15) * 8;
  const ushort* vSrc = VT + hb + (long)(tid >> 3) * SEQ + (tid & 7) * 8;
  const int kOff = (tid >> 4) * 136 + (tid & 15) * 8;
  const int vOff = (tid >> 3) * 72 + (tid & 7) * 8;

  // prologue: stage tile 0 into buf 0
  {
    bf16x8 kR[4], vR[4];
#pragma unroll
    for (int it = 0; it < 4; it++) {
      kR[it] = *(const bf16x8*)(kSrc + (long)it * (16 * HDIM));
      vR[it] = *(const bf16x8*)(vSrc + (long)it * (32 * SEQ));
    }
    kSrc += 64 * HDIM; vSrc += 64;
#pragma unroll
    for (int it = 0; it < 4; it++) {
      *(bf16x8*)(smem + kOff + it * (16 * 136)) = kR[it];
      *(bf16x8*)(smem + 17408 + vOff + it * (32 * 72)) = vR[it];
    }
  }
  __syncthreads();

  for (int t0 = 0; t0 < SEQ; t0 += 64) {
    const int cur = (t0 >> 6) & 1;
    ushort* cK = cur ? smem + 8704 : smem;
    ushort* cV = cur ? smem + 26624 : smem + 17408;
    ushort* nK = cur ? smem : smem + 8704;
    ushort* nV = cur ? smem + 17408 : smem + 26624;
    const bool more = (t0 + 64 < SEQ);

    // issue next tile's global loads (consumed after PV)
    bf16x8 kR[4], vR[4];
    if (more) {
#pragma unroll
      for (int it = 0; it < 4; it++) {
        kR[it] = *(const bf16x8*)(kSrc + (long)it * (16 * HDIM));
        vR[it] = *(const bf16x8*)(vSrc + (long)it * (32 * SEQ));
      }
      kSrc += 64 * HDIM; vSrc += 64;
    }

    // S^T = K Q^T over this wave's 32x32 tile: A=K (m=t), B=Q (n=q)
    const ushort* kRow = cK + (th * 32 + l16) * 136 + (quad << 3);
    f32x4 st[2][2] = {};  // [tt][qq]
    __builtin_amdgcn_s_setprio(1);
#pragma unroll
    for (int kc = 0; kc < 4; kc++)
#pragma unroll
      for (int tt = 0; tt < 2; tt++) {
        const bf16x8 ka = *(const bf16x8*)(kRow + tt * (16 * 136) + kc * 32);
#pragma unroll
        for (int qq = 0; qq < 2; qq++)
          st[tt][qq] = __builtin_amdgcn_mfma_f32_16x16x32_bf16(
              ka, qa[qq][kc], st[tt][qq], 0, 0, 0);
      }
    __builtin_amdgcn_s_setprio(0);

    // p = 2^s (Q carries log2e): lane's q = qq*16+l16 (col),
    // t = tt*16+quad*4+r (row reg) -> one b64 store per (qq,tt).
    ushort* pW = myP + l16 * 40 + (quad << 2);
#pragma unroll
    for (int qq = 0; qq < 2; qq++)
#pragma unroll
      for (int tt = 0; tt < 2; tt++) {
        ushort4 pk;
        pk.x = f2bf_rhu(fast_exp2(st[tt][qq][0]));
        pk.y = f2bf_rhu(fast_exp2(st[tt][qq][1]));
        pk.z = f2bf_rhu(fast_exp2(st[tt][qq][2]));
        pk.w = f2bf_rhu(fast_exp2(st[tt][qq][3]));
        *(ushort4*)(pW + qq * (16 * 40) + tt * 16) = pk;
      }
    WAITL();                               // P is wave-private: lgkm only
    __builtin_amdgcn_sched_barrier(0);     // rule 18: pin vs hoisting

    // PV: A=P (m=q, k=t from one b128), B=VT rows (n=d, k=t)
    const ushort* pRow = myP + l16 * 40 + (quad << 3);
    const ushort* vRow = cV + l16 * 72 + th * 32 + (quad << 3);
    bf16x8 pa[2];
    __builtin_amdgcn_s_setprio(1);
#pragma unroll
    for (int qq = 0; qq < 2; qq++) {
      pa[qq] = *(const bf16x8*)(pRow + qq * (16 * 40));
      lacc[qq] = __builtin_amdgcn_mfma_f32_16x16x32_bf16(
          pa[qq], ones, lacc[qq], 0, 0, 0);
    }
#pragma unroll
    for (int nt = 0; nt < 8; nt++) {
      const bf16x8 vb = *(const bf16x8*)(vRow + nt * (16 * 72));
#pragma unroll
      for (int qq = 0; qq < 2; qq++)
        o[qq][nt] = __builtin_amdgcn_mfma_f32_16x16x32_bf16(
            pa[qq], vb, o[qq][nt], 0, 0, 0);
    }
    __builtin_amdgcn_s_setprio(0);

    // land staged regs in the alternate buffer; single barrier per iter:
    // guards next-iter reads of nK/nV AND next-iter overwrites of cK/cV.
    if (more) {
#pragma unroll
      for (int it = 0; it < 4; it++) {
        *(bf16x8*)(nK + kOff + it * (16 * 136)) = kR[it];
        *(bf16x8*)(nV + vOff + it * (32 * 72)) = vR[it];
      }
    }
    __syncthreads();
  }

  // Merge t-halves: waves 2,3 publish (O, l); waves 0,1 add and store.
  float* mb = (float*)smem;  // 2 regions x 64 lanes x 73 floats = 37376 B
  if (wave >= 2) {
    float* p = mb + ((wave - 2) * 64 + lane) * 73;
#pragma unroll
    for (int qq = 0; qq < 2; qq++) {
#pragma unroll
      for (int nt = 0; nt < 8; nt++)
#pragma unroll
        for (int r = 0; r < 4; r++) p[qq * 32 + nt * 4 + r] = o[qq][nt][r];
#pragma unroll
      for (int r = 0; r < 4; r++) p[64 + qq * 4 + r] = lacc[qq][r];
    }
  }
  __syncthreads();
  if (wave < 2) {
    const float* p = mb + (wave * 64 + lane) * 73;
#pragma unroll
    for (int qq = 0; qq < 2; qq++) {
#pragma unroll
      for (int nt = 0; nt < 8; nt++)
#pragma unroll
        for (int r = 0; r < 4; r++) o[qq][nt][r] += p[qq * 32 + nt * 4 + r];
#pragma unroll
      for (int r = 0; r < 4; r++) lacc[qq][r] += p[64 + qq * 4 + r];
    }
#pragma unroll
    for (int qq = 0; qq < 2; qq++)
#pragma unroll
      for (int r = 0; r < 4; r++) {
        const float inv = 1.0f / lacc[qq][r];
        const int s = qt * 64 + qh * 32 + qq * 16 + quad * 4 + r;
        const long base = ((long)(b * SEQ + s)) * DMODEL + h * HDIM;
#pragma unroll
        for (int nt = 0; nt < 8; nt++)
          ctx[base + nt * 16 + l16] = f2bf(o[qq][nt][r] * inv);
      }
  }
}

// ---------------------------------------------------------------------------
extern "C" void kernel_launch(void* const* d_in, const int* in_sizes, int n_in,
                              void* d_out, int out_size, void* d_ws, size_t ws_size,
                              hipStream_t stream) {
  const float* hid = (const float*)d_in[0];
  const float* Wq = (const float*)d_in[1];
  const float* bq = (const float*)d_in[2];
  const float* Wk = (const float*)d_in[3];
  const float* bk = (const float*)d_in[4];
  const float* Wv = (const float*)d_in[5];
  const float* bv = (const float*)d_in[6];
  const float* Wo = (const float*)d_in[7];
  const float* bo = (const float*)d_in[8];
  float* out = (float*)d_out;
  ushort* ws = (ushort*)d_ws;

  ushort* qw   = ws;            // [B,H,S,HD] bf16  (Q/K/V contiguous!)
  ushort* kw   = ws + NEL;
  ushort* vw   = ws + 2 * NEL;  // reused as ctx after transpose_v
  ushort* hidB = ws + 3 * NEL;  // hidden bf16; reused as VT after QKV GEMM(s)
  ushort* wB   = ws + 4 * NEL;  // weight bf16: 1x or 3x [D,D]

  dim3 blk(256);
  dim3 blkG(512);
  conv_f32_bf16<<<(int)(NEL / 4 / 256), blk, 0, stream>>>(hid, hidB, NEL / 4);

  if (ws_size >= FUSED_WS) {
    // fused QKV: one N=6144 GEMM, (4096/256)*(6144/256) = 384 blocks
    conv_f32_bf16<<<(int)(WEL / 4 / 256), blk, 0, stream>>>(Wq, wB, WEL / 4);
    conv_f32_bf16<<<(int)(WEL / 4 / 256), blk, 0, stream>>>(Wk, wB + WEL, WEL / 4);
    conv_f32_bf16<<<(int)(WEL / 4 / 256), blk, 0, stream>>>(Wv, wB + 2 * WEL, WEL / 4);
    float* bc = (float*)(wB + 3 * WEL);
    bias_cat<<<24, blk, 0, stream>>>(bq, bk, bv, bc);
    gemm256<1><<<384, blkG, 0, stream>>>(hidB, wB, bc, qw, MTOT, 3 * DMODEL, DMODEL);
  } else {
    conv_f32_bf16<<<(int)(WEL / 4 / 256), blk, 0, stream>>>(Wq, wB, WEL / 4);
    gemm256<1><<<128, blkG, 0, stream>>>(hidB, wB, bq, qw, MTOT, DMODEL, DMODEL);
    conv_f32_bf16<<<(int)(WEL / 4 / 256), blk, 0, stream>>>(Wk, wB, WEL / 4);
    gemm256<1><<<128, blkG, 0, stream>>>(hidB, wB, bk, kw, MTOT, DMODEL, DMODEL);
    conv_f32_bf16<<<(int)(WEL / 4 / 256), blk, 0, stream>>>(Wv, wB, WEL / 4);
    gemm256<1><<<128, blkG, 0, stream>>>(hidB, wB, bv, vw, MTOT, DMODEL, DMODEL);
  }

  rope_qk<<<32768, blk, 0, stream>>>(qw, kw);

  // V^T into the hidB slot (hidden no longer needed as GEMM input)
  ushort* vtw = hidB;
  transpose_v<<<2048, blk, 0, stream>>>(vw, vtw);

  // attn writes ctx into the vw slot (V superseded by VT)
  ushort* cw = vw;
  attn<<<1024, blk, 0, stream>>>(qw, kw, vtw, cw);

  conv_f32_bf16<<<(int)(WEL / 4 / 256), blk, 0, stream>>>(Wo, wB, WEL / 4);
  gemm256<0><<<128, blkG, 0, stream>>>(cw, wB, bo, out, MTOT, DMODEL, DMODEL);
}

// Round 4
// 423.060 us; speedup vs baseline: 1.1869x; 1.0197x over previous
//
#include <hip/hip_runtime.h>

constexpr int NH = 16;
constexpr int SEQ = 2048;
constexpr int DMODEL = 2048;
constexpr int HDIM = 128;
constexpr int NB = 2;
constexpr int MTOT = NB * SEQ;                 // 4096
constexpr long NEL = (long)NB * SEQ * DMODEL;  // 8388608 activation elements
constexpr long WEL = (long)DMODEL * DMODEL;    // 4194304 weight elements
// fused-QKV workspace requirement (bytes): 4 activations + 3 weights + bias cat
constexpr size_t FUSED_WS = 2ul * (4 * NEL + 3 * WEL + 12288);

typedef __attribute__((ext_vector_type(8))) __bf16 bf16x8;
typedef __attribute__((ext_vector_type(4))) float f32x4;

__device__ __forceinline__ float bf2f(ushort u) {
  union { uint i; float f; } v; v.i = ((uint)u) << 16; return v.f;
}
__device__ __forceinline__ ushort f2bf(float f) {
  union { float f; uint i; } v; v.f = f;
  uint r = (v.i + 0x7FFFu + ((v.i >> 16) & 1u)) >> 16;
  return (ushort)r;
}
// round-half-up bf16: 2 VALU ops; P>0 so tie bias is negligible (hot path only)
__device__ __forceinline__ ushort f2bf_rhu(float f) {
  union { float f; uint i; } v; v.f = f;
  return (ushort)((v.i + 0x8000u) >> 16);
}
__device__ __forceinline__ float fast_exp2(float x) {
#if __has_builtin(__builtin_amdgcn_exp2f)
  return __builtin_amdgcn_exp2f(x);
#else
  float r;
  asm volatile("v_exp_f32 %0, %1\n\ts_nop 0" : "=v"(r) : "v"(x));
  return r;
#endif
}

// ---------------------------------------------------------------------------
// fp32 -> bf16 conversion (inputs are float32 per the reference contract).
// ---------------------------------------------------------------------------
__global__ __launch_bounds__(256) void conv_f32_bf16(
    const float* __restrict__ s, ushort* __restrict__ d, int n4) {
  const int i = blockIdx.x * 256 + threadIdx.x;
  if (i < n4) {
    const float4 v = ((const float4*)s)[i];
    ushort4 o;
    o.x = f2bf(v.x); o.y = f2bf(v.y); o.z = f2bf(v.z); o.w = f2bf(v.w);
    ((ushort4*)d)[i] = o;
  }
}

// concat 3 x 2048 fp32 biases for the fused QKV GEMM
__global__ __launch_bounds__(256) void bias_cat(
    const float* __restrict__ a, const float* __restrict__ b,
    const float* __restrict__ c, float* __restrict__ o) {
  const int i = blockIdx.x * 256 + threadIdx.x;  // grid 24 -> 6144
  o[i] = (i < 2048) ? a[i] : (i < 4096) ? b[i - 2048] : c[i - 4096];
}

// ---------------------------------------------------------------------------
// 128x256-tile 2-phase/K-tile bt-GEMM: C[M,N] = A[M,K]@B[N,K]^T + bias.
// R4: retiled so grids divide 256 CUs exactly (fused QKV 32x24=768 = 3 exact
// rounds; out-proj 32x8=256 = 1 round) — R3 counters showed per-active-CU
// MfmaUtil ~58% (template-level) and the whole deficit was idle-CU rounds
// (384 blocks -> 75% duty; out-proj 128 blocks -> 50%).
// 8 waves (2M x 4N), per-wave 64x64 output, BK=64, LDS 96 KiB double-buffer.
// Phase p consumes B-col-half p (16 MFMA); counted vmcnt (8/6) keeps 3-4
// half-tiles in flight, never drains in-loop; next-phase ds_reads issue
// after each MFMA cluster (latency hides under barrier); T2 XOR swizzle on
// global source + ds_read; T5 setprio. MODE 0: fp32 [M,N]. MODE 1: bf16
// scatter to [B,H,S,HD], col>>11 selects the tensor (Q/K/V contiguous).
// ---------------------------------------------------------------------------
#define GLDS(src, dst)                                              \
  __builtin_amdgcn_global_load_lds(                                 \
      (const __attribute__((address_space(1))) void*)(src),         \
      (__attribute__((address_space(3))) void*)(dst), 16, 0, 0)

// A tile 128x64 (2 loads/thread); B tile 256x64 staged as two 128-row halves
#define STG_A(d, kt) do {                                           \
    const ushort* _s = gA + (long)(kt) * 64;                        \
    ushort* _d = smem + (d) * 8192 + w * 512;                       \
    GLDS(_s, _d);                                                   \
    GLDS(_s + 64 * (long)K, _d + 4096);                             \
  } while (0)

#define STG_B0(d, kt) do {                                          \
    const ushort* _s = gB + (long)(kt) * 64;                        \
    ushort* _d = smem + 16384 + (d) * 16384 + w * 512;              \
    GLDS(_s, _d);                                                   \
    GLDS(_s + 64 * (long)K, _d + 4096);                             \
  } while (0)

#define STG_B1(d, kt) do {                                          \
    const ushort* _s = gB + 128 * (long)K + (long)(kt) * 64;        \
    ushort* _d = smem + 16384 + (d) * 16384 + 8192 + w * 512;       \
    GLDS(_s, _d);                                                   \
    GLDS(_s + 64 * (long)K, _d + 4096);                             \
  } while (0)

#define LDAF(d) do {                                                \
    const ushort* _p = smem + (d) * 8192 + (wm * 64 + l16) * 64;    \
    _Pragma("unroll")                                               \
    for (int _i = 0; _i < 4; _i++) {                                \
      afr[_i][0] = *(const bf16x8*)(_p + _i * 1024 + sw0);          \
      afr[_i][1] = *(const bf16x8*)(_p + _i * 1024 + sw1);          \
    }                                                               \
  } while (0)

#define LDBF(d, nh) do {                                            \
    const ushort* _p = smem + 16384 + (d) * 16384 +                 \
                       ((nh) * 128 + wn * 32 + l16) * 64;           \
    _Pragma("unroll")                                               \
    for (int _j = 0; _j < 2; _j++) {                                \
      bfr[nh][_j][0] = *(const bf16x8*)(_p + _j * 1024 + sw0);      \
      bfr[nh][_j][1] = *(const bf16x8*)(_p + _j * 1024 + sw1);      \
    }                                                               \
  } while (0)

#define MMAP(nh) do {                                               \
    __builtin_amdgcn_s_setprio(1);                                  \
    _Pragma("unroll")                                               \
    for (int _i = 0; _i < 4; _i++)                                  \
      _Pragma("unroll")                                             \
      for (int _j = 0; _j < 2; _j++) {                              \
        acc[_i][(nh) * 2 + _j] = __builtin_amdgcn_mfma_f32_16x16x32_bf16( \
            afr[_i][0], bfr[nh][_j][0], acc[_i][(nh) * 2 + _j], 0, 0, 0); \
        acc[_i][(nh) * 2 + _j] = __builtin_amdgcn_mfma_f32_16x16x32_bf16( \
            afr[_i][1], bfr[nh][_j][1], acc[_i][(nh) * 2 + _j], 0, 0, 0); \
      }                                                             \
    __builtin_amdgcn_s_setprio(0);                                  \
  } while (0)

#define BARX() __builtin_amdgcn_s_barrier()
#define WAITV(n) asm volatile("s_waitcnt vmcnt(" #n ")" ::: "memory")
#define WAITL() asm volatile("s_waitcnt lgkmcnt(0)" ::: "memory")

template <int MODE>
__global__ __launch_bounds__(512, 2) void gemm128(
    const ushort* __restrict__ A, const ushort* __restrict__ Bw,
    const float* __restrict__ bias, void* __restrict__ Cv,
    int M, int N, int K) {
  // LDS (ushort units): A[2][128][64] @ 0 (8192/buf); B[2][256][64] @ 16384
  // (16384/buf). 96 KiB total -> 1 block/CU.
  __shared__ __align__(16) ushort smem[49152];
  const int tid = threadIdx.x;
  const int w = tid >> 6, lane = tid & 63;
  const int quad = lane >> 4, l16 = lane & 15;
  const int wm = w >> 2, wn = w & 3;  // 2M x 4N waves, per-wave 64x64
  const int nbm = M >> 7, nbn = N >> 8;
  // Two-level XCD partition: 8 regions (2 along M x 4 along N), each rm x rn
  // blocks, column-major within a region.
  const int rm = nbm >> 1, rn = nbn >> 2;
  const int xcd = blockIdx.x & 7, loc = blockIdx.x >> 3;
  const int bm = (xcd >> 2) * rm + (loc % rm);
  const int bn = (xcd & 3) * rn + (loc / rm);
  const int m0 = bm << 7, n0 = bn << 8;
  const int KT = K >> 6;  // 64-wide K-tiles (K=2048 -> 32)

  // staging source: thread -> row tid/8 (+64/128/192 per sweep), 16B chunk
  // (tid&7) XOR (row&7) == pre-swizzled source (global_load_lds dst linear)
  const int srow = tid >> 3;
  const int scol = (((tid & 7) ^ ((tid >> 3) & 7)) << 3);
  const ushort* gA = A + (long)(m0 + srow) * K + scol;
  const ushort* gB = Bw + (long)(n0 + srow) * K + scol;
  // ds_read swizzled 16B-slot offsets for kk=0/1: slot=(kk*4+quad)^(row&7),
  // row&7 == l16&7 for all fragment rows.
  const int sw0 = ((quad ^ (l16 & 7)) << 3);
  const int sw1 = (((4 + quad) ^ (l16 & 7)) << 3);

  f32x4 acc[4][4] = {};   // [m-frag][nh*2+j]
  bf16x8 afr[4][2];       // A frags [m-frag][kk]
  bf16x8 bfr[2][2][2];    // B frags [nh][j][kk]

  // Prologue: B1(0),A(0),B0(0) landed (WAITV(4)); A(1),B0(1) in flight.
  STG_B1(0, 0);
  STG_A(0, 0); STG_B0(0, 0);
  STG_A(1, 1); STG_B0(1, 1);
  WAITV(4);
  BARX();
  LDAF(0); LDBF(0, 0);
  WAITL();
  BARX();  // all waves' prologue ds_reads retired before any loop staging

  for (int t = 0; t < KT; t++) {
    const int d = t & 1, nd = d ^ 1;
    const int c1 = (t + 1 < KT) ? t + 1 : 0;             // phantom -> L2-hot
    const int c2 = (t + 2 < KT) ? t + 2 : (t + 2 - KT);
    // ---- phase 0: C-cols 0..127 of this tile ----
    STG_B1(nd, c1);          // B1(t+1)
    STG_A(d, c2);            // A(t+2) over A(t) (last read 1 barrier ago)
    WAITV(8);                // newest 8 = A(t+2),B1(t+1),B0(t+1),A(t+1)
    BARX();
    WAITL();
    MMAP(0);                 // afr=A(t), bfr0=B0(t)
    LDBF(d, 1);              // B1(t) -> bfr1 (latency hides under barrier)
    BARX();
    // ---- phase 1: C-cols 128..255 ----
    STG_B0(d, c2);           // B0(t+2) over B0(t)
    WAITV(6);                // newest 6 = B0(t+2),A(t+2),B1(t+1)
    BARX();
    WAITL();
    MMAP(1);                 // afr=A(t), bfr1=B1(t)
    LDAF(nd); LDBF(nd, 0);   // A(t+1), B0(t+1) for next iteration
    BARX();
  }

  // Epilogue: C layout col=l16, row=quad*4+r.
#pragma unroll
  for (int i = 0; i < 4; i++) {
    const int rbase = m0 + wm * 64 + i * 16 + quad * 4;
#pragma unroll
    for (int nh = 0; nh < 2; nh++)
#pragma unroll
      for (int j = 0; j < 2; j++) {
        const int col = n0 + nh * 128 + wn * 32 + j * 16 + l16;
        const float bv = bias[col];
#pragma unroll
        for (int r = 0; r < 4; r++) {
          const int row = rbase + r;
          const float v = acc[i][nh * 2 + j][r] + bv;
          if (MODE == 0) {
            ((float*)Cv)[(long)row * N + col] = v;
          } else {
            const int b = row >> 11, s = row & (SEQ - 1);
            const int h = (col >> 7) & 15, hd = col & (HDIM - 1);
            const long off = (long)(col >> 11) * NEL +
                ((long)(b * NH + h) * SEQ + s) * HDIM + hd;
            ((ushort*)Cv)[off] = f2bf(v);
          }
        }
      }
  }
}

// ---------------------------------------------------------------------------
// RoPE in-place on bf16 Q,K in [B,H,S,HD]; reference swaps sin/cos.
// Q pre-scaled by log2(e)/sqrt(HD) so attn uses bare exp2 for softmax.
// sin/cos via revolution-domain v_sin/v_cos (explicit fract reduction);
// phase error ~1.3e-4 rad << bf16 quantization.
// ---------------------------------------------------------------------------
__global__ __launch_bounds__(256) void rope_qk(ushort* Q, ushort* Kt) {
  const int gid = blockIdx.x * 256 + threadIdx.x;
  const int n = gid & 4194303;
  const bool isK = (gid >= 4194304);
  ushort* ptr = isK ? Kt : Q;
  const float qs = isK ? 1.0f : 0.12751743f;  // log2(e)/sqrt(128)
  const int p = n & 63;
  const int s = (n >> 6) & (SEQ - 1);
  const int bh = n >> 17;
  const long idx = (long)bh * (SEQ * HDIM) + (long)s * HDIM + p;
  // inv_freq / (2*pi): angle in revolutions
  const float invf_rev =
      fast_exp2(-(float)p * 0.2076205059304601f) * 0.15915494309189535f;
  float rev = (float)s * invf_rev;
  rev -= floorf(rev);
  const float sn = __builtin_amdgcn_sinf(rev);
  const float cs = __builtin_amdgcn_cosf(rev);
  const float x1 = bf2f(ptr[idx]);
  const float x2 = bf2f(ptr[idx + 64]);
  ptr[idx]      = f2bf((x1 * sn - x2 * cs) * qs);
  ptr[idx + 64] = f2bf((x2 * sn + x1 * cs) * qs);
}

// ---------------------------------------------------------------------------
// V transpose per head: [B,H,S,HD] -> [B,H,HD,S], 64x64 LDS tiles.
// ---------------------------------------------------------------------------
__global__ __launch_bounds__(256) void transpose_v(const ushort* __restrict__ V,
                                                   ushort* __restrict__ VT) {
  __shared__ ushort lT[64 * 65];
  const int bh = blockIdx.x >> 6;
  const int rem = blockIdx.x & 63;
  const int t0 = (rem >> 1) << 6, d0 = (rem & 1) << 6;
  const ushort* vb = V + (long)bh * (SEQ * HDIM);
  ushort* ob = VT + (long)bh * (SEQ * HDIM);
  const int tid = threadIdx.x;
#pragma unroll
  for (int it = 0; it < 16; it++) {
    const int idx = it * 256 + tid;
    const int r = idx >> 6, c = idx & 63;
    lT[c * 65 + r] = vb[(long)(t0 + r) * HDIM + d0 + c];
  }
  __syncthreads();
#pragma unroll
  for (int it = 0; it < 16; it++) {
    const int idx = it * 256 + tid;
    const int r = idx >> 6, c = idx & 63;
    ob[(long)(d0 + r) * SEQ + t0 + c] = lT[r * 65 + c];
  }
}

// ---------------------------------------------------------------------------
// Flash attention, fixed-max softmax, S^T-form QK (S^T = K*Q^T).
// Double-buffered K/V staging (T14 async reg split) -> ONE barrier per
// t-iteration. P scratch wave-private (lgkmcnt-only ordering). Softmax is
// bare exp2 (Q pre-scaled by log2e in rope). T5 setprio on MFMA clusters.
// LDS 80 KB exactly -> 2 blocks/CU.
// ---------------------------------------------------------------------------
__global__ __launch_bounds__(256, 2) void attn(const ushort* __restrict__ Q,
                                               const ushort* __restrict__ Kp,
                                               const ushort* __restrict__ VT,
                                               ushort* __restrict__ ctx) {
  // lK[2]: [64][136] @ 0 / 8704 ; lV[2]: [128][72] @ 17408 / 26624 ;
  // lP: 4 x [32][40] @ 35840.  Total 40960 ushort = 80 KiB.
  __shared__ __align__(16) ushort smem[40960];
  const int tid = threadIdx.x;
  const int wave = tid >> 6, lane = tid & 63;
  const int quad = lane >> 4, l16 = lane & 15;
  // XCD-aware swizzle: 128 consecutive local ids (4 heads) per XCD.
  const int xcd = blockIdx.x & 7, loc = blockIdx.x >> 3;
  const int bh = xcd * 4 + (loc >> 5), qt = loc & 31;
  const long hb = (long)bh * (SEQ * HDIM);
  const int b = bh >> 4, h = bh & 15;
  const int qh = wave & 1, th = wave >> 1;
  ushort* myP = smem + 35840 + wave * (32 * 40);

  // Q fragments (B-operand: n=q=l16, k=hd=quad*8+j) for both 16-q subtiles
  bf16x8 qa[2][4];
#pragma unroll
  for (int qq = 0; qq < 2; qq++)
#pragma unroll
    for (int c = 0; c < 4; c++)
      qa[qq][c] = *(const bf16x8*)(
          Q + hb + (long)(qt * 64 + qh * 32 + qq * 16 + l16) * HDIM +
          c * 32 + (quad << 3));

  f32x4 o[2][8] = {};
  f32x4 lacc[2] = {};
  bf16x8 ones;
#pragma unroll
  for (int i = 0; i < 8; i++) ones[i] = (__bf16)1.0f;

  // staging addressing (per-thread), buffer-relative
  const ushort* kSrc = Kp + hb + (long)(tid >> 4) * HDIM + (tid & 15) * 8;
  const ushort* vSrc = VT + hb + (long)(tid >> 3) * SEQ + (tid & 7) * 8;
  const int kOff = (tid >> 4) * 136 + (tid & 15) * 8;
  const int vOff = (tid >> 3) * 72 + (tid & 7) * 8;

  // prologue: stage tile 0 into buf 0
  {
    bf16x8 kR[4], vR[4];
#pragma unroll
    for (int it = 0; it < 4; it++) {
      kR[it] = *(const bf16x8*)(kSrc + (long)it * (16 * HDIM));
      vR[it] = *(const bf16x8*)(vSrc + (long)it * (32 * SEQ));
    }
    kSrc += 64 * HDIM; vSrc += 64;
#pragma unroll
    for (int it = 0; it < 4; it++) {
      *(bf16x8*)(smem + kOff + it * (16 * 136)) = kR[it];
      *(bf16x8*)(smem + 17408 + vOff + it * (32 * 72)) = vR[it];
    }
  }
  __syncthreads();

  for (int t0 = 0; t0 < SEQ; t0 += 64) {
    const int cur = (t0 >> 6) & 1;
    ushort* cK = cur ? smem + 8704 : smem;
    ushort* cV = cur ? smem + 26624 : smem + 17408;
    ushort* nK = cur ? smem : smem + 8704;
    ushort* nV = cur ? smem + 17408 : smem + 26624;
    const bool more = (t0 + 64 < SEQ);

    // issue next tile's global loads (consumed after PV)
    bf16x8 kR[4], vR[4];
    if (more) {
#pragma unroll
      for (int it = 0; it < 4; it++) {
        kR[it] = *(const bf16x8*)(kSrc + (long)it * (16 * HDIM));
        vR[it] = *(const bf16x8*)(vSrc + (long)it * (32 * SEQ));
      }
      kSrc += 64 * HDIM; vSrc += 64;
    }

    // S^T = K Q^T over this wave's 32x32 tile: A=K (m=t), B=Q (n=q)
    const ushort* kRow = cK + (th * 32 + l16) * 136 + (quad << 3);
    f32x4 st[2][2] = {};  // [tt][qq]
    __builtin_amdgcn_s_setprio(1);
#pragma unroll
    for (int kc = 0; kc < 4; kc++)
#pragma unroll
      for (int tt = 0; tt < 2; tt++) {
        const bf16x8 ka = *(const bf16x8*)(kRow + tt * (16 * 136) + kc * 32);
#pragma unroll
        for (int qq = 0; qq < 2; qq++)
          st[tt][qq] = __builtin_amdgcn_mfma_f32_16x16x32_bf16(
              ka, qa[qq][kc], st[tt][qq], 0, 0, 0);
      }
    __builtin_amdgcn_s_setprio(0);

    // p = 2^s (Q carries log2e): lane's q = qq*16+l16 (col),
    // t = tt*16+quad*4+r (row reg) -> one b64 store per (qq,tt).
    ushort* pW = myP + l16 * 40 + (quad << 2);
#pragma unroll
    for (int qq = 0; qq < 2; qq++)
#pragma unroll
      for (int tt = 0; tt < 2; tt++) {
        ushort4 pk;
        pk.x = f2bf_rhu(fast_exp2(st[tt][qq][0]));
        pk.y = f2bf_rhu(fast_exp2(st[tt][qq][1]));
        pk.z = f2bf_rhu(fast_exp2(st[tt][qq][2]));
        pk.w = f2bf_rhu(fast_exp2(st[tt][qq][3]));
        *(ushort4*)(pW + qq * (16 * 40) + tt * 16) = pk;
      }
    WAITL();                               // P is wave-private: lgkm only
    __builtin_amdgcn_sched_barrier(0);     // rule 18: pin vs hoisting

    // PV: A=P (m=q, k=t from one b128), B=VT rows (n=d, k=t)
    const ushort* pRow = myP + l16 * 40 + (quad << 3);
    const ushort* vRow = cV + l16 * 72 + th * 32 + (quad << 3);
    bf16x8 pa[2];
    __builtin_amdgcn_s_setprio(1);
#pragma unroll
    for (int qq = 0; qq < 2; qq++) {
      pa[qq] = *(const bf16x8*)(pRow + qq * (16 * 40));
      lacc[qq] = __builtin_amdgcn_mfma_f32_16x16x32_bf16(
          pa[qq], ones, lacc[qq], 0, 0, 0);
    }
#pragma unroll
    for (int nt = 0; nt < 8; nt++) {
      const bf16x8 vb = *(const bf16x8*)(vRow + nt * (16 * 72));
#pragma unroll
      for (int qq = 0; qq < 2; qq++)
        o[qq][nt] = __builtin_amdgcn_mfma_f32_16x16x32_bf16(
            pa[qq], vb, o[qq][nt], 0, 0, 0);
    }
    __builtin_amdgcn_s_setprio(0);

    // land staged regs in the alternate buffer; single barrier per iter:
    // guards next-iter reads of nK/nV AND next-iter overwrites of cK/cV.
    if (more) {
#pragma unroll
      for (int it = 0; it < 4; it++) {
        *(bf16x8*)(nK + kOff + it * (16 * 136)) = kR[it];
        *(bf16x8*)(nV + vOff + it * (32 * 72)) = vR[it];
      }
    }
    __syncthreads();
  }

  // Merge t-halves: waves 2,3 publish (O, l); waves 0,1 add and store.
  float* mb = (float*)smem;  // 2 regions x 64 lanes x 73 floats = 37376 B
  if (wave >= 2) {
    float* p = mb + ((wave - 2) * 64 + lane) * 73;
#pragma unroll
    for (int qq = 0; qq < 2; qq++) {
#pragma unroll
      for (int nt = 0; nt < 8; nt++)
#pragma unroll
        for (int r = 0; r < 4; r++) p[qq * 32 + nt * 4 + r] = o[qq][nt][r];
#pragma unroll
      for (int r = 0; r < 4; r++) p[64 + qq * 4 + r] = lacc[qq][r];
    }
  }
  __syncthreads();
  if (wave < 2) {
    const float* p = mb + (wave * 64 + lane) * 73;
#pragma unroll
    for (int qq = 0; qq < 2; qq++) {
#pragma unroll
      for (int nt = 0; nt < 8; nt++)
#pragma unroll
        for (int r = 0; r < 4; r++) o[qq][nt][r] += p[qq * 32 + nt * 4 + r];
#pragma unroll
      for (int r = 0; r < 4; r++) lacc[qq][r] += p[64 + qq * 4 + r];
    }
#pragma unroll
    for (int qq = 0; qq < 2; qq++)
#pragma unroll
      for (int r = 0; r < 4; r++) {
        const float inv = 1.0f / lacc[qq][r];
        const int s = qt * 64 + qh * 32 + qq * 16 + quad * 4 + r;
        const long base = ((long)(b * SEQ + s)) * DMODEL + h * HDIM;
#pragma unroll
        for (int nt = 0; nt < 8; nt++)
          ctx[base + nt * 16 + l16] = f2bf(o[qq][nt][r] * inv);
      }
  }
}

// ---------------------------------------------------------------------------
extern "C" void kernel_launch(void* const* d_in, const int* in_sizes, int n_in,
                              void* d_out, int out_size, void* d_ws, size_t ws_size,
                              hipStream_t stream) {
  const float* hid = (const float*)d_in[0];
  const float* Wq = (const float*)d_in[1];
  const float* bq = (const float*)d_in[2];
  const float* Wk = (const float*)d_in[3];
  const float* bk = (const float*)d_in[4];
  const float* Wv = (const float*)d_in[5];
  const float* bv = (const float*)d_in[6];
  const float* Wo = (const float*)d_in[7];
  const float* bo = (const float*)d_in[8];
  float* out = (float*)d_out;
  ushort* ws = (ushort*)d_ws;

  ushort* qw   = ws;            // [B,H,S,HD] bf16  (Q/K/V contiguous!)
  ushort* kw   = ws + NEL;
  ushort* vw   = ws + 2 * NEL;  // reused as ctx after transpose_v
  ushort* hidB = ws + 3 * NEL;  // hidden bf16; reused as VT after QKV GEMM(s)
  ushort* wB   = ws + 4 * NEL;  // weight bf16: 1x or 3x [D,D]

  dim3 blk(256);
  dim3 blkG(512);
  conv_f32_bf16<<<(int)(NEL / 4 / 256), blk, 0, stream>>>(hid, hidB, NEL / 4);

  if (ws_size >= FUSED_WS) {
    // fused QKV: one N=6144 GEMM, (4096/128)*(6144/256) = 768 = 3 exact rounds
    conv_f32_bf16<<<(int)(WEL / 4 / 256), blk, 0, stream>>>(Wq, wB, WEL / 4);
    conv_f32_bf16<<<(int)(WEL / 4 / 256), blk, 0, stream>>>(Wk, wB + WEL, WEL / 4);
    conv_f32_bf16<<<(int)(WEL / 4 / 256), blk, 0, stream>>>(Wv, wB + 2 * WEL, WEL / 4);
    float* bc = (float*)(wB + 3 * WEL);
    bias_cat<<<24, blk, 0, stream>>>(bq, bk, bv, bc);
    gemm128<1><<<768, blkG, 0, stream>>>(hidB, wB, bc, qw, MTOT, 3 * DMODEL, DMODEL);
  } else {
    conv_f32_bf16<<<(int)(WEL / 4 / 256), blk, 0, stream>>>(Wq, wB, WEL / 4);
    gemm128<1><<<256, blkG, 0, stream>>>(hidB, wB, bq, qw, MTOT, DMODEL, DMODEL);
    conv_f32_bf16<<<(int)(WEL / 4 / 256), blk, 0, stream>>>(Wk, wB, WEL / 4);
    gemm128<1><<<256, blkG, 0, stream>>>(hidB, wB, bk, kw, MTOT, DMODEL, DMODEL);
    conv_f32_bf16<<<(int)(WEL / 4 / 256), blk, 0, stream>>>(Wv, wB, WEL / 4);
    gemm128<1><<<256, blkG, 0, stream>>>(hidB, wB, bv, vw, MTOT, DMODEL, DMODEL);
  }

  rope_qk<<<32768, blk, 0, stream>>>(qw, kw);

  // V^T into the hidB slot (hidden no longer needed as GEMM input)
  ushort* vtw = hidB;
  transpose_v<<<2048, blk, 0, stream>>>(vw, vtw);

  // attn writes ctx into the vw slot (V superseded by VT)
  ushort* cw = vw;
  attn<<<1024, blk, 0, stream>>>(qw, kw, vtw, cw);

  // out-projection: 32*8 = 256 blocks = exactly 1 round
  conv_f32_bf16<<<(int)(WEL / 4 / 256), blk, 0, stream>>>(Wo, wB, WEL / 4);
  gemm128<0><<<256, blkG, 0, stream>>>(cw, wB, bo, out, MTOT, DMODEL, DMODEL);
}

// Round 5
// 403.304 us; speedup vs baseline: 1.2451x; 1.0490x over previous
//
#include <hip/hip_runtime.h>

constexpr int NH = 16;
constexpr int SEQ = 2048;
constexpr int DMODEL = 2048;
constexpr int HDIM = 128;
constexpr int NB = 2;
constexpr int MTOT = NB * SEQ;                 // 4096
constexpr long NEL = (long)NB * SEQ * DMODEL;  // 8388608 activation elements
constexpr long WEL = (long)DMODEL * DMODEL;    // 4194304 weight elements
// fused-QKV workspace requirement (bytes): 4 activations + 3 weights + bias cat
constexpr size_t FUSED_WS = 2ul * (4 * NEL + 3 * WEL + 12288);

typedef __attribute__((ext_vector_type(8))) __bf16 bf16x8;
typedef __attribute__((ext_vector_type(4))) float f32x4;

__device__ __forceinline__ float bf2f(ushort u) {
  union { uint i; float f; } v; v.i = ((uint)u) << 16; return v.f;
}
__device__ __forceinline__ ushort f2bf(float f) {
  union { float f; uint i; } v; v.f = f;
  uint r = (v.i + 0x7FFFu + ((v.i >> 16) & 1u)) >> 16;
  return (ushort)r;
}
// round-half-up bf16: 2 VALU ops; P>0 so tie bias is negligible (hot path only)
__device__ __forceinline__ ushort f2bf_rhu(float f) {
  union { float f; uint i; } v; v.f = f;
  return (ushort)((v.i + 0x8000u) >> 16);
}
__device__ __forceinline__ float fast_exp2(float x) {
#if __has_builtin(__builtin_amdgcn_exp2f)
  return __builtin_amdgcn_exp2f(x);
#else
  float r;
  asm volatile("v_exp_f32 %0, %1\n\ts_nop 0" : "=v"(r) : "v"(x));
  return r;
#endif
}

// ---------------------------------------------------------------------------
// fp32 -> bf16 conversion (inputs are float32 per the reference contract).
// ---------------------------------------------------------------------------
__global__ __launch_bounds__(256) void conv_f32_bf16(
    const float* __restrict__ s, ushort* __restrict__ d, int n4) {
  const int i = blockIdx.x * 256 + threadIdx.x;
  if (i < n4) {
    const float4 v = ((const float4*)s)[i];
    ushort4 o;
    o.x = f2bf(v.x); o.y = f2bf(v.y); o.z = f2bf(v.z); o.w = f2bf(v.w);
    ((ushort4*)d)[i] = o;
  }
}

// concat 3 x 2048 fp32 biases for the fused QKV GEMM
__global__ __launch_bounds__(256) void bias_cat(
    const float* __restrict__ a, const float* __restrict__ b,
    const float* __restrict__ c, float* __restrict__ o) {
  const int i = blockIdx.x * 256 + threadIdx.x;  // grid 24 -> 6144
  o[i] = (i < 2048) ? a[i] : (i < 4096) ? b[i - 2048] : c[i - 4096];
}

// ---------------------------------------------------------------------------
// Shared GEMM plumbing: global_load_lds + XOR swizzle (T2) both-sides.
// ---------------------------------------------------------------------------
#define GLDS(src, dst)                                              \
  __builtin_amdgcn_global_load_lds(                                 \
      (const __attribute__((address_space(1))) void*)(src),         \
      (__attribute__((address_space(3))) void*)(dst), 16, 0, 0)

#define BARX() __builtin_amdgcn_s_barrier()
#define WAITV(n) asm volatile("s_waitcnt vmcnt(" #n ")" ::: "memory")
#define WAITL() asm volatile("s_waitcnt lgkmcnt(0)" ::: "memory")

// ---------------------------------------------------------------------------
// gemm384: 128x384-tile, 3-phase/K-tile bt-GEMM (m201-heft phases at 100%
// duty). C[M,N] = A[M,K]@B[N,K]^T + bias. 8 waves (2M x 4N), per-wave 64x96,
// BK=64, LDS 128 KiB (A 2x16KB, B 2x48KB in three 128-row thirds).
// Grid (fused QKV): 32x16 = 512 = 2 exact rounds on 256 CUs.
// R5 theory: R3 showed per-active-CU 49% at 75% duty; R4 showed 37% at 100%
// duty (2-phase heft collapse). This keeps 16 MFMA/wave/phase (m201 heft),
// 8 MFMA/barrier, counted vmcnt(10) at ph0/ph2 only (derived from issue
// order: per tile ph0 issues B2(t+1),A(t+2); ph1 B0(t+2); ph2 B1(t+2)).
// T2 swizzle on global source + ds_read; T5 setprio. MODE 1 bf16 scatter.
// ---------------------------------------------------------------------------
#define G3_STG_A(d, kt) do {                                        \
    const ushort* _s = gA + (long)(kt) * 64;                        \
    ushort* _d = smem + (d) * 8192 + w * 512;                       \
    GLDS(_s, _d);                                                   \
    GLDS(_s + 64 * (long)K, _d + 4096);                             \
  } while (0)

#define G3_STG_B(d, j, kt) do {                                     \
    const ushort* _s = gB + (long)(j) * 128 * K + (long)(kt) * 64;  \
    ushort* _d = smem + 16384 + (d) * 24576 + (j) * 8192 + w * 512; \
    GLDS(_s, _d);                                                   \
    GLDS(_s + 64 * (long)K, _d + 4096);                             \
  } while (0)

#define G3_LDA(d) do {                                              \
    const ushort* _p = smem + (d) * 8192 + (wm * 64 + l16) * 64;    \
    _Pragma("unroll")                                               \
    for (int _i = 0; _i < 4; _i++) {                                \
      afr[_i][0] = *(const bf16x8*)(_p + _i * 1024 + sw0);          \
      afr[_i][1] = *(const bf16x8*)(_p + _i * 1024 + sw1);          \
    }                                                               \
  } while (0)

#define G3_LDB(d, j, s) do {                                        \
    const ushort* _p = smem + 16384 + (d) * 24576 + (j) * 8192 +    \
                       (wn * 32 + l16) * 64;                        \
    _Pragma("unroll")                                               \
    for (int _j = 0; _j < 2; _j++) {                                \
      bfr[s][_j][0] = *(const bf16x8*)(_p + _j * 1024 + sw0);       \
      bfr[s][_j][1] = *(const bf16x8*)(_p + _j * 1024 + sw1);       \
    }                                                               \
  } while (0)

#define G3_MMA(s, j) do {                                           \
    __builtin_amdgcn_s_setprio(1);                                  \
    _Pragma("unroll")                                               \
    for (int _i = 0; _i < 4; _i++)                                  \
      _Pragma("unroll")                                             \
      for (int _j = 0; _j < 2; _j++) {                              \
        acc[_i][(j) * 2 + _j] = __builtin_amdgcn_mfma_f32_16x16x32_bf16( \
            afr[_i][0], bfr[s][_j][0], acc[_i][(j) * 2 + _j], 0, 0, 0);  \
        acc[_i][(j) * 2 + _j] = __builtin_amdgcn_mfma_f32_16x16x32_bf16( \
            afr[_i][1], bfr[s][_j][1], acc[_i][(j) * 2 + _j], 0, 0, 0);  \
      }                                                             \
    __builtin_amdgcn_s_setprio(0);                                  \
  } while (0)

template <int MODE>
__global__ __launch_bounds__(512, 2) void gemm384(
    const ushort* __restrict__ A, const ushort* __restrict__ Bw,
    const float* __restrict__ bias, void* __restrict__ Cv,
    int M, int N, int K) {
  // LDS (ushort units): A[2][128][64] @ 0 (8192/buf); B[2][384][64] @ 16384
  // (24576/buf, thirds of 8192). 128 KiB -> 1 block/CU.
  __shared__ __align__(16) ushort smem[65536];
  const int tid = threadIdx.x;
  const int w = tid >> 6, lane = tid & 63;
  const int quad = lane >> 4, l16 = lane & 15;
  const int wm = w >> 2, wn = w & 3;  // 2M x 4N waves, per-wave 64x96
  const int nbm = M >> 7, nbn = N / 384;
  // Two-level XCD partition: 8 regions (2 along M x 4 along N)
  const int rm = nbm >> 1, rn = nbn >> 2;
  const int xcd = blockIdx.x & 7, loc = blockIdx.x >> 3;
  const int bm = (xcd >> 2) * rm + (loc % rm);
  const int bn = (xcd & 3) * rn + (loc / rm);
  const int m0 = bm << 7, n0 = bn * 384;
  const int KT = K >> 6;  // K=2048 -> 32 (even)

  const int srow = tid >> 3;
  const int scol = (((tid & 7) ^ ((tid >> 3) & 7)) << 3);
  const ushort* gA = A + (long)(m0 + srow) * K + scol;
  const ushort* gB = Bw + (long)(n0 + srow) * K + scol;
  const int sw0 = ((quad ^ (l16 & 7)) << 3);
  const int sw1 = (((4 + quad) ^ (l16 & 7)) << 3);

  f32x4 acc[4][6] = {};   // [m-frag][third*2 + j]
  bf16x8 afr[4][2];       // A frags [m-frag][kk]
  bf16x8 bfr[2][2][2];    // B frag sets [set][j][kk]

  // Prologue: A(0),B0(0),B1(0),B2(0),A(1),B0(1),B1(1) = 7 units (14 loads).
  // WAITV(10) lands A(0),B0(0) -- exactly what the initial reads need; the
  // same count then holds at every ph0/ph2 with no special-casing.
  G3_STG_A(0, 0);
  G3_STG_B(0, 0, 0); G3_STG_B(0, 1, 0); G3_STG_B(0, 2, 0);
  G3_STG_A(1, 1);
  G3_STG_B(1, 0, 1); G3_STG_B(1, 1, 1);
  WAITV(10);
  BARX();
  G3_LDA(0); G3_LDB(0, 0, 0);
  WAITL();
  BARX();

  for (int t = 0; t < KT; t += 2) {
    const int e2 = (t + 2 < KT) ? t + 2 : 0;   // phantom -> L2-hot
    const int e3 = (t + 3 < KT) ? t + 3 : 1;
    // ================= tile t (buf 0) =================
    // ph0: MMA B0(t); stage B2(t+1)->buf1, A(t+2)->buf0
    G3_STG_B(1, 2, t + 1);
    G3_STG_A(0, e2);
    WAITV(10); BARX(); WAITL();
    G3_MMA(0, 0);
    G3_LDB(0, 1, 1);          // B1(t) -> set1
    BARX();
    // ph1: MMA B1(t); stage B0(t+2)->buf0
    G3_STG_B(0, 0, e2);
    BARX(); WAITL();
    G3_MMA(1, 1);
    G3_LDB(0, 2, 0);          // B2(t) -> set0
    BARX();
    // ph2: MMA B2(t); stage B1(t+2)->buf0; prefetch A(t+1), B0(t+1)
    G3_STG_B(0, 1, e2);
    WAITV(10); BARX(); WAITL();
    G3_MMA(0, 2);
    G3_LDA(1);                // A(t+1)
    G3_LDB(1, 0, 1);          // B0(t+1) -> set1
    BARX();
    // ================= tile t+1 (buf 1) =================
    // ph0: MMA B0(t+1); stage B2(t+2)->buf0, A(t+3)->buf1
    G3_STG_B(0, 2, e2);
    G3_STG_A(1, e3);
    WAITV(10); BARX(); WAITL();
    G3_MMA(1, 0);
    G3_LDB(1, 1, 0);          // B1(t+1) -> set0
    BARX();
    // ph1: MMA B1(t+1); stage B0(t+3)->buf1
    G3_STG_B(1, 0, e3);
    BARX(); WAITL();
    G3_MMA(0, 1);
    G3_LDB(1, 2, 1);          // B2(t+1) -> set1
    BARX();
    // ph2: MMA B2(t+1); stage B1(t+3)->buf1; prefetch A(t+2), B0(t+2)
    G3_STG_B(1, 1, e3);
    WAITV(10); BARX(); WAITL();
    G3_MMA(1, 2);
    G3_LDA(0);                // A(t+2)
    G3_LDB(0, 0, 0);          // B0(t+2) -> set0
    BARX();
  }

  // Epilogue: C layout col=l16, row=quad*4+r.
#pragma unroll
  for (int i = 0; i < 4; i++) {
    const int rbase = m0 + wm * 64 + i * 16 + quad * 4;
#pragma unroll
    for (int jt = 0; jt < 3; jt++)
#pragma unroll
      for (int j = 0; j < 2; j++) {
        const int col = n0 + jt * 128 + wn * 32 + j * 16 + l16;
        const float bv = bias[col];
#pragma unroll
        for (int r = 0; r < 4; r++) {
          const int row = rbase + r;
          const float v = acc[i][jt * 2 + j][r] + bv;
          if (MODE == 0) {
            ((float*)Cv)[(long)row * N + col] = v;
          } else {
            const int b = row >> 11, s = row & (SEQ - 1);
            const int h = (col >> 7) & 15, hd = col & (HDIM - 1);
            const long off = (long)(col >> 11) * NEL +
                ((long)(b * NH + h) * SEQ + s) * HDIM + hd;
            ((ushort*)Cv)[off] = f2bf(v);
          }
        }
      }
  }
}

// ---------------------------------------------------------------------------
// gemm128: 128x256-tile 2-phase bt-GEMM (R4) — kept for N=2048 shapes where
// 384 doesn't divide N: out-projection (grid 256 = 1 exact round) and the
// non-fused fallback path.
// ---------------------------------------------------------------------------
#define STG_A(d, kt) do {                                           \
    const ushort* _s = gA + (long)(kt) * 64;                        \
    ushort* _d = smem + (d) * 8192 + w * 512;                       \
    GLDS(_s, _d);                                                   \
    GLDS(_s + 64 * (long)K, _d + 4096);                             \
  } while (0)

#define STG_B0(d, kt) do {                                          \
    const ushort* _s = gB + (long)(kt) * 64;                        \
    ushort* _d = smem + 16384 + (d) * 16384 + w * 512;              \
    GLDS(_s, _d);                                                   \
    GLDS(_s + 64 * (long)K, _d + 4096);                             \
  } while (0)

#define STG_B1(d, kt) do {                                          \
    const ushort* _s = gB + 128 * (long)K + (long)(kt) * 64;        \
    ushort* _d = smem + 16384 + (d) * 16384 + 8192 + w * 512;       \
    GLDS(_s, _d);                                                   \
    GLDS(_s + 64 * (long)K, _d + 4096);                             \
  } while (0)

#define LDAF(d) do {                                                \
    const ushort* _p = smem + (d) * 8192 + (wm * 64 + l16) * 64;    \
    _Pragma("unroll")                                               \
    for (int _i = 0; _i < 4; _i++) {                                \
      afr[_i][0] = *(const bf16x8*)(_p + _i * 1024 + sw0);          \
      afr[_i][1] = *(const bf16x8*)(_p + _i * 1024 + sw1);          \
    }                                                               \
  } while (0)

#define LDBF(d, nh) do {                                            \
    const ushort* _p = smem + 16384 + (d) * 16384 +                 \
                       ((nh) * 128 + wn * 32 + l16) * 64;           \
    _Pragma("unroll")                                               \
    for (int _j = 0; _j < 2; _j++) {                                \
      bfr[nh][_j][0] = *(const bf16x8*)(_p + _j * 1024 + sw0);      \
      bfr[nh][_j][1] = *(const bf16x8*)(_p + _j * 1024 + sw1);      \
    }                                                               \
  } while (0)

#define MMAP(nh) do {                                               \
    __builtin_amdgcn_s_setprio(1);                                  \
    _Pragma("unroll")                                               \
    for (int _i = 0; _i < 4; _i++)                                  \
      _Pragma("unroll")                                             \
      for (int _j = 0; _j < 2; _j++) {                              \
        acc[_i][(nh) * 2 + _j] = __builtin_amdgcn_mfma_f32_16x16x32_bf16( \
            afr[_i][0], bfr[nh][_j][0], acc[_i][(nh) * 2 + _j], 0, 0, 0); \
        acc[_i][(nh) * 2 + _j] = __builtin_amdgcn_mfma_f32_16x16x32_bf16( \
            afr[_i][1], bfr[nh][_j][1], acc[_i][(nh) * 2 + _j], 0, 0, 0); \
      }                                                             \
    __builtin_amdgcn_s_setprio(0);                                  \
  } while (0)

template <int MODE>
__global__ __launch_bounds__(512, 2) void gemm128(
    const ushort* __restrict__ A, const ushort* __restrict__ Bw,
    const float* __restrict__ bias, void* __restrict__ Cv,
    int M, int N, int K) {
  __shared__ __align__(16) ushort smem[49152];
  const int tid = threadIdx.x;
  const int w = tid >> 6, lane = tid & 63;
  const int quad = lane >> 4, l16 = lane & 15;
  const int wm = w >> 2, wn = w & 3;
  const int nbm = M >> 7, nbn = N >> 8;
  const int rm = nbm >> 1, rn = nbn >> 2;
  const int xcd = blockIdx.x & 7, loc = blockIdx.x >> 3;
  const int bm = (xcd >> 2) * rm + (loc % rm);
  const int bn = (xcd & 3) * rn + (loc / rm);
  const int m0 = bm << 7, n0 = bn << 8;
  const int KT = K >> 6;

  const int srow = tid >> 3;
  const int scol = (((tid & 7) ^ ((tid >> 3) & 7)) << 3);
  const ushort* gA = A + (long)(m0 + srow) * K + scol;
  const ushort* gB = Bw + (long)(n0 + srow) * K + scol;
  const int sw0 = ((quad ^ (l16 & 7)) << 3);
  const int sw1 = (((4 + quad) ^ (l16 & 7)) << 3);

  f32x4 acc[4][4] = {};
  bf16x8 afr[4][2];
  bf16x8 bfr[2][2][2];

  STG_B1(0, 0);
  STG_A(0, 0); STG_B0(0, 0);
  STG_A(1, 1); STG_B0(1, 1);
  WAITV(4);
  BARX();
  LDAF(0); LDBF(0, 0);
  WAITL();
  BARX();

  for (int t = 0; t < KT; t++) {
    const int d = t & 1, nd = d ^ 1;
    const int c1 = (t + 1 < KT) ? t + 1 : 0;
    const int c2 = (t + 2 < KT) ? t + 2 : (t + 2 - KT);
    STG_B1(nd, c1);
    STG_A(d, c2);
    WAITV(8);
    BARX();
    WAITL();
    MMAP(0);
    LDBF(d, 1);
    BARX();
    STG_B0(d, c2);
    WAITV(6);
    BARX();
    WAITL();
    MMAP(1);
    LDAF(nd); LDBF(nd, 0);
    BARX();
  }

#pragma unroll
  for (int i = 0; i < 4; i++) {
    const int rbase = m0 + wm * 64 + i * 16 + quad * 4;
#pragma unroll
    for (int nh = 0; nh < 2; nh++)
#pragma unroll
      for (int j = 0; j < 2; j++) {
        const int col = n0 + nh * 128 + wn * 32 + j * 16 + l16;
        const float bv = bias[col];
#pragma unroll
        for (int r = 0; r < 4; r++) {
          const int row = rbase + r;
          const float v = acc[i][nh * 2 + j][r] + bv;
          if (MODE == 0) {
            ((float*)Cv)[(long)row * N + col] = v;
          } else {
            const int b = row >> 11, s = row & (SEQ - 1);
            const int h = (col >> 7) & 15, hd = col & (HDIM - 1);
            const long off = (long)(col >> 11) * NEL +
                ((long)(b * NH + h) * SEQ + s) * HDIM + hd;
            ((ushort*)Cv)[off] = f2bf(v);
          }
        }
      }
  }
}

// ---------------------------------------------------------------------------
// RoPE in-place on bf16 Q,K in [B,H,S,HD]; reference swaps sin/cos.
// Q pre-scaled by log2(e)/sqrt(HD) so attn uses bare exp2 for softmax.
// ---------------------------------------------------------------------------
__global__ __launch_bounds__(256) void rope_qk(ushort* Q, ushort* Kt) {
  const int gid = blockIdx.x * 256 + threadIdx.x;
  const int n = gid & 4194303;
  const bool isK = (gid >= 4194304);
  ushort* ptr = isK ? Kt : Q;
  const float qs = isK ? 1.0f : 0.12751743f;  // log2(e)/sqrt(128)
  const int p = n & 63;
  const int s = (n >> 6) & (SEQ - 1);
  const int bh = n >> 17;
  const long idx = (long)bh * (SEQ * HDIM) + (long)s * HDIM + p;
  const float invf_rev =
      fast_exp2(-(float)p * 0.2076205059304601f) * 0.15915494309189535f;
  float rev = (float)s * invf_rev;
  rev -= floorf(rev);
  const float sn = __builtin_amdgcn_sinf(rev);
  const float cs = __builtin_amdgcn_cosf(rev);
  const float x1 = bf2f(ptr[idx]);
  const float x2 = bf2f(ptr[idx + 64]);
  ptr[idx]      = f2bf((x1 * sn - x2 * cs) * qs);
  ptr[idx + 64] = f2bf((x2 * sn + x1 * cs) * qs);
}

// ---------------------------------------------------------------------------
// V transpose per head: [B,H,S,HD] -> [B,H,HD,S], 64x64 LDS tiles.
// ---------------------------------------------------------------------------
__global__ __launch_bounds__(256) void transpose_v(const ushort* __restrict__ V,
                                                   ushort* __restrict__ VT) {
  __shared__ ushort lT[64 * 65];
  const int bh = blockIdx.x >> 6;
  const int rem = blockIdx.x & 63;
  const int t0 = (rem >> 1) << 6, d0 = (rem & 1) << 6;
  const ushort* vb = V + (long)bh * (SEQ * HDIM);
  ushort* ob = VT + (long)bh * (SEQ * HDIM);
  const int tid = threadIdx.x;
#pragma unroll
  for (int it = 0; it < 16; it++) {
    const int idx = it * 256 + tid;
    const int r = idx >> 6, c = idx & 63;
    lT[c * 65 + r] = vb[(long)(t0 + r) * HDIM + d0 + c];
  }
  __syncthreads();
#pragma unroll
  for (int it = 0; it < 16; it++) {
    const int idx = it * 256 + tid;
    const int r = idx >> 6, c = idx & 63;
    ob[(long)(d0 + r) * SEQ + t0 + c] = lT[r * 65 + c];
  }
}

// ---------------------------------------------------------------------------
// Flash attention, fixed-max softmax, S^T-form QK (S^T = K*Q^T).
// Double-buffered K/V staging (T14) -> ONE barrier per t-iteration.
// P scratch wave-private. Softmax bare exp2. T5 setprio. LDS 80 KB.
// ---------------------------------------------------------------------------
__global__ __launch_bounds__(256, 2) void attn(const ushort* __restrict__ Q,
                                               const ushort* __restrict__ Kp,
                                               const ushort* __restrict__ VT,
                                               ushort* __restrict__ ctx) {
  __shared__ __align__(16) ushort smem[40960];
  const int tid = threadIdx.x;
  const int wave = tid >> 6, lane = tid & 63;
  const int quad = lane >> 4, l16 = lane & 15;
  const int xcd = blockIdx.x & 7, loc = blockIdx.x >> 3;
  const int bh = xcd * 4 + (loc >> 5), qt = loc & 31;
  const long hb = (long)bh * (SEQ * HDIM);
  const int b = bh >> 4, h = bh & 15;
  const int qh = wave & 1, th = wave >> 1;
  ushort* myP = smem + 35840 + wave * (32 * 40);

  bf16x8 qa[2][4];
#pragma unroll
  for (int qq = 0; qq < 2; qq++)
#pragma unroll
    for (int c = 0; c < 4; c++)
      qa[qq][c] = *(const bf16x8*)(
          Q + hb + (long)(qt * 64 + qh * 32 + qq * 16 + l16) * HDIM +
          c * 32 + (quad << 3));

  f32x4 o[2][8] = {};
  f32x4 lacc[2] = {};
  bf16x8 ones;
#pragma unroll
  for (int i = 0; i < 8; i++) ones[i] = (__bf16)1.0f;

  const ushort* kSrc = Kp + hb + (long)(tid >> 4) * HDIM + (tid & 15) * 8;
  const ushort* vSrc = VT + hb + (long)(tid >> 3) * SEQ + (tid & 7) * 8;
  const int kOff = (tid >> 4) * 136 + (tid & 15) * 8;
  const int vOff = (tid >> 3) * 72 + (tid & 7) * 8;

  {
    bf16x8 kR[4], vR[4];
#pragma unroll
    for (int it = 0; it < 4; it++) {
      kR[it] = *(const bf16x8*)(kSrc + (long)it * (16 * HDIM));
      vR[it] = *(const bf16x8*)(vSrc + (long)it * (32 * SEQ));
    }
    kSrc += 64 * HDIM; vSrc += 64;
#pragma unroll
    for (int it = 0; it < 4; it++) {
      *(bf16x8*)(smem + kOff + it * (16 * 136)) = kR[it];
      *(bf16x8*)(smem + 17408 + vOff + it * (32 * 72)) = vR[it];
    }
  }
  __syncthreads();

  for (int t0 = 0; t0 < SEQ; t0 += 64) {
    const int cur = (t0 >> 6) & 1;
    ushort* cK = cur ? smem + 8704 : smem;
    ushort* cV = cur ? smem + 26624 : smem + 17408;
    ushort* nK = cur ? smem : smem + 8704;
    ushort* nV = cur ? smem + 17408 : smem + 26624;
    const bool more = (t0 + 64 < SEQ);

    bf16x8 kR[4], vR[4];
    if (more) {
#pragma unroll
      for (int it = 0; it < 4; it++) {
        kR[it] = *(const bf16x8*)(kSrc + (long)it * (16 * HDIM));
        vR[it] = *(const bf16x8*)(vSrc + (long)it * (32 * SEQ));
      }
      kSrc += 64 * HDIM; vSrc += 64;
    }

    const ushort* kRow = cK + (th * 32 + l16) * 136 + (quad << 3);
    f32x4 st[2][2] = {};
    __builtin_amdgcn_s_setprio(1);
#pragma unroll
    for (int kc = 0; kc < 4; kc++)
#pragma unroll
      for (int tt = 0; tt < 2; tt++) {
        const bf16x8 ka = *(const bf16x8*)(kRow + tt * (16 * 136) + kc * 32);
#pragma unroll
        for (int qq = 0; qq < 2; qq++)
          st[tt][qq] = __builtin_amdgcn_mfma_f32_16x16x32_bf16(
              ka, qa[qq][kc], st[tt][qq], 0, 0, 0);
      }
    __builtin_amdgcn_s_setprio(0);

    ushort* pW = myP + l16 * 40 + (quad << 2);
#pragma unroll
    for (int qq = 0; qq < 2; qq++)
#pragma unroll
      for (int tt = 0; tt < 2; tt++) {
        ushort4 pk;
        pk.x = f2bf_rhu(fast_exp2(st[tt][qq][0]));
        pk.y = f2bf_rhu(fast_exp2(st[tt][qq][1]));
        pk.z = f2bf_rhu(fast_exp2(st[tt][qq][2]));
        pk.w = f2bf_rhu(fast_exp2(st[tt][qq][3]));
        *(ushort4*)(pW + qq * (16 * 40) + tt * 16) = pk;
      }
    WAITL();
    __builtin_amdgcn_sched_barrier(0);

    const ushort* pRow = myP + l16 * 40 + (quad << 3);
    const ushort* vRow = cV + l16 * 72 + th * 32 + (quad << 3);
    bf16x8 pa[2];
    __builtin_amdgcn_s_setprio(1);
#pragma unroll
    for (int qq = 0; qq < 2; qq++) {
      pa[qq] = *(const bf16x8*)(pRow + qq * (16 * 40));
      lacc[qq] = __builtin_amdgcn_mfma_f32_16x16x32_bf16(
          pa[qq], ones, lacc[qq], 0, 0, 0);
    }
#pragma unroll
    for (int nt = 0; nt < 8; nt++) {
      const bf16x8 vb = *(const bf16x8*)(vRow + nt * (16 * 72));
#pragma unroll
      for (int qq = 0; qq < 2; qq++)
        o[qq][nt] = __builtin_amdgcn_mfma_f32_16x16x32_bf16(
            pa[qq], vb, o[qq][nt], 0, 0, 0);
    }
    __builtin_amdgcn_s_setprio(0);

    if (more) {
#pragma unroll
      for (int it = 0; it < 4; it++) {
        *(bf16x8*)(nK + kOff + it * (16 * 136)) = kR[it];
        *(bf16x8*)(nV + vOff + it * (32 * 72)) = vR[it];
      }
    }
    __syncthreads();
  }

  float* mb = (float*)smem;
  if (wave >= 2) {
    float* p = mb + ((wave - 2) * 64 + lane) * 73;
#pragma unroll
    for (int qq = 0; qq < 2; qq++) {
#pragma unroll
      for (int nt = 0; nt < 8; nt++)
#pragma unroll
        for (int r = 0; r < 4; r++) p[qq * 32 + nt * 4 + r] = o[qq][nt][r];
#pragma unroll
      for (int r = 0; r < 4; r++) p[64 + qq * 4 + r] = lacc[qq][r];
    }
  }
  __syncthreads();
  if (wave < 2) {
    const float* p = mb + (wave * 64 + lane) * 73;
#pragma unroll
    for (int qq = 0; qq < 2; qq++) {
#pragma unroll
      for (int nt = 0; nt < 8; nt++)
#pragma unroll
        for (int r = 0; r < 4; r++) o[qq][nt][r] += p[qq * 32 + nt * 4 + r];
#pragma unroll
      for (int r = 0; r < 4; r++) lacc[qq][r] += p[64 + qq * 4 + r];
    }
#pragma unroll
    for (int qq = 0; qq < 2; qq++)
#pragma unroll
      for (int r = 0; r < 4; r++) {
        const float inv = 1.0f / lacc[qq][r];
        const int s = qt * 64 + qh * 32 + qq * 16 + quad * 4 + r;
        const long base = ((long)(b * SEQ + s)) * DMODEL + h * HDIM;
#pragma unroll
        for (int nt = 0; nt < 8; nt++)
          ctx[base + nt * 16 + l16] = f2bf(o[qq][nt][r] * inv);
      }
  }
}

// ---------------------------------------------------------------------------
extern "C" void kernel_launch(void* const* d_in, const int* in_sizes, int n_in,
                              void* d_out, int out_size, void* d_ws, size_t ws_size,
                              hipStream_t stream) {
  const float* hid = (const float*)d_in[0];
  const float* Wq = (const float*)d_in[1];
  const float* bq = (const float*)d_in[2];
  const float* Wk = (const float*)d_in[3];
  const float* bk = (const float*)d_in[4];
  const float* Wv = (const float*)d_in[5];
  const float* bv = (const float*)d_in[6];
  const float* Wo = (const float*)d_in[7];
  const float* bo = (const float*)d_in[8];
  float* out = (float*)d_out;
  ushort* ws = (ushort*)d_ws;

  ushort* qw   = ws;            // [B,H,S,HD] bf16  (Q/K/V contiguous!)
  ushort* kw   = ws + NEL;
  ushort* vw   = ws + 2 * NEL;  // reused as ctx after transpose_v
  ushort* hidB = ws + 3 * NEL;  // hidden bf16; reused as VT after QKV GEMM(s)
  ushort* wB   = ws + 4 * NEL;  // weight bf16: 1x or 3x [D,D]

  dim3 blk(256);
  dim3 blkG(512);
  conv_f32_bf16<<<(int)(NEL / 4 / 256), blk, 0, stream>>>(hid, hidB, NEL / 4);

  if (ws_size >= FUSED_WS) {
    // fused QKV: one N=6144 GEMM, (4096/128)*(6144/384) = 512 = 2 exact rounds
    conv_f32_bf16<<<(int)(WEL / 4 / 256), blk, 0, stream>>>(Wq, wB, WEL / 4);
    conv_f32_bf16<<<(int)(WEL / 4 / 256), blk, 0, stream>>>(Wk, wB + WEL, WEL / 4);
    conv_f32_bf16<<<(int)(WEL / 4 / 256), blk, 0, stream>>>(Wv, wB + 2 * WEL, WEL / 4);
    float* bc = (float*)(wB + 3 * WEL);
    bias_cat<<<24, blk, 0, stream>>>(bq, bk, bv, bc);
    gemm384<1><<<512, blkG, 0, stream>>>(hidB, wB, bc, qw, MTOT, 3 * DMODEL, DMODEL);
  } else {
    conv_f32_bf16<<<(int)(WEL / 4 / 256), blk, 0, stream>>>(Wq, wB, WEL / 4);
    gemm128<1><<<256, blkG, 0, stream>>>(hidB, wB, bq, qw, MTOT, DMODEL, DMODEL);
    conv_f32_bf16<<<(int)(WEL / 4 / 256), blk, 0, stream>>>(Wk, wB, WEL / 4);
    gemm128<1><<<256, blkG, 0, stream>>>(hidB, wB, bk, kw, MTOT, DMODEL, DMODEL);
    conv_f32_bf16<<<(int)(WEL / 4 / 256), blk, 0, stream>>>(Wv, wB, WEL / 4);
    gemm128<1><<<256, blkG, 0, stream>>>(hidB, wB, bv, vw, MTOT, DMODEL, DMODEL);
  }

  rope_qk<<<32768, blk, 0, stream>>>(qw, kw);

  // V^T into the hidB slot (hidden no longer needed as GEMM input)
  ushort* vtw = hidB;
  transpose_v<<<2048, blk, 0, stream>>>(vw, vtw);

  // attn writes ctx into the vw slot (V superseded by VT)
  ushort* cw = vw;
  attn<<<1024, blk, 0, stream>>>(qw, kw, vtw, cw);

  // out-projection: 32*8 = 256 blocks = exactly 1 round
  conv_f32_bf16<<<(int)(WEL / 4 / 256), blk, 0, stream>>>(Wo, wB, WEL / 4);
  gemm128<0><<<256, blkG, 0, stream>>>(cw, wB, bo, out, MTOT, DMODEL, DMODEL);
}